// Round 3
// baseline (4204.650 us; speedup 1.0000x reference)
//
#include <hip/hip_runtime.h>
#include <stdint.h>

#define DF 128
typedef unsigned short ushort_t;
typedef __attribute__((ext_vector_type(8))) short short8v;   // 8 bf16 (4 VGPRs)
typedef __attribute__((ext_vector_type(4))) float f32x4;

// ---------------- Threefry-2x32 (JAX-compatible, 20 rounds) ----------------
__host__ __device__ __forceinline__ unsigned rotl32(unsigned v, int r) {
  return (v << r) | (v >> (32 - r));
}

__host__ __device__ __forceinline__ void threefry2x32(
    unsigned k0, unsigned k1, unsigned c0, unsigned c1,
    unsigned& o0, unsigned& o1) {
  unsigned kx = k0 ^ k1 ^ 0x1BD11BDAu;
  unsigned x0 = c0 + k0;
  unsigned x1 = c1 + k1;
#define TF_R(r) { x0 += x1; x1 = rotl32(x1, r); x1 ^= x0; }
  TF_R(13) TF_R(15) TF_R(26) TF_R(6)
  x0 += k1; x1 += kx + 1u;
  TF_R(17) TF_R(29) TF_R(16) TF_R(24)
  x0 += kx; x1 += k0 + 2u;
  TF_R(13) TF_R(15) TF_R(26) TF_R(6)
  x0 += k0; x1 += k1 + 3u;
  TF_R(17) TF_R(29) TF_R(16) TF_R(24)
  x0 += k1; x1 += kx + 4u;
  TF_R(13) TF_R(15) TF_R(26) TF_R(6)
  x0 += kx; x1 += k0 + 5u;
#undef TF_R
  o0 = x0; o1 = x1;
}

#define KEEP_THR 0xE6666600u   // uniform(bits) < 0.9f

// ---------------- bf16 helpers (RTNE) --------------------------------------
__device__ __forceinline__ ushort_t f2bf(float f) {
  unsigned u = __float_as_uint(f);
  unsigned r = (u + 0x7fffu + ((u >> 16) & 1u)) >> 16;
  return (ushort_t)r;
}

// ---------------- MFMA GEMM [M,128] x [128,128] ----------------------------
// EPI 0: outB = bf16(X@W1)
// EPI 1: outF = relu(X@W1 + acc1/max(cnt1,1))
// EPI 2: outF = relu(0.5*(X@(W1+W2) + acc1/n1 + acc2/n2))
// Block 256 = 4 waves; BM=128. mfma_f32_16x16x32_bf16;
// C/D: col=lane&15, row=(lane>>4)*4+j. A/B k-map symmetric (permutation-safe).
template <int EPI>
__global__ __launch_bounds__(256) void gemm_mfma(
    const float* __restrict__ X, const float* __restrict__ W1,
    const float* __restrict__ W2, int M,
    ushort_t* __restrict__ outB, float* __restrict__ outF,
    const float* __restrict__ acc1, const unsigned* __restrict__ cnt1,
    const float* __restrict__ acc2, const unsigned* __restrict__ cnt2) {
  __shared__ ushort_t Wt[DF][136];   // W^T bf16, padded
  const int t = threadIdx.x;
  const int lane = t & 63;
  const int w = t >> 6;
  const int lr = lane & 15;     // A-row / B-col within 16
  const int kg = lane >> 4;     // k-group 0..3
  const int rbase = blockIdx.x * 128;

  // stage W (optionally W1+W2) transposed as bf16
#pragma unroll
  for (int i = 0; i < 16; ++i) {
    int q = t + i * 256;
    int k = q >> 5;
    int c4 = (q & 31) * 4;
    float4 wv = *reinterpret_cast<const float4*>(&W1[k * DF + c4]);
    if constexpr (EPI == 2) {
      float4 w2 = *reinterpret_cast<const float4*>(&W2[k * DF + c4]);
      wv.x += w2.x; wv.y += w2.y; wv.z += w2.z; wv.w += w2.w;
    }
    Wt[c4 + 0][k] = f2bf(wv.x);
    Wt[c4 + 1][k] = f2bf(wv.y);
    Wt[c4 + 2][k] = f2bf(wv.z);
    Wt[c4 + 3][k] = f2bf(wv.w);
  }
  __syncthreads();

  f32x4 acc[2][8];
#pragma unroll
  for (int rg = 0; rg < 2; ++rg)
#pragma unroll
    for (int n = 0; n < 8; ++n) acc[rg][n] = (f32x4){0.f, 0.f, 0.f, 0.f};

#pragma unroll
  for (int kt = 0; kt < 4; ++kt) {
    const int kb = kt * 32 + kg * 8;
    short8v a[2];
#pragma unroll
    for (int rg = 0; rg < 2; ++rg) {
      int r = rbase + w * 32 + rg * 16 + lr;
      float4 x0 = make_float4(0.f, 0.f, 0.f, 0.f);
      float4 x1 = x0;
      if (r < M) {
        x0 = *reinterpret_cast<const float4*>(&X[(size_t)r * DF + kb]);
        x1 = *reinterpret_cast<const float4*>(&X[(size_t)r * DF + kb + 4]);
      }
      short8v av;
      av[0] = (short)f2bf(x0.x); av[1] = (short)f2bf(x0.y);
      av[2] = (short)f2bf(x0.z); av[3] = (short)f2bf(x0.w);
      av[4] = (short)f2bf(x1.x); av[5] = (short)f2bf(x1.y);
      av[6] = (short)f2bf(x1.z); av[7] = (short)f2bf(x1.w);
      a[rg] = av;
    }
#pragma unroll
    for (int n = 0; n < 8; ++n) {
      short8v b = *reinterpret_cast<const short8v*>(&Wt[n * 16 + lr][kb]);
#pragma unroll
      for (int rg = 0; rg < 2; ++rg)
        acc[rg][n] = __builtin_amdgcn_mfma_f32_16x16x32_bf16(a[rg], b, acc[rg][n], 0, 0, 0);
    }
  }

  // epilogue
#pragma unroll
  for (int rg = 0; rg < 2; ++rg) {
    const int rb = rbase + w * 32 + rg * 16 + kg * 4;
    float inv1[4], inv2[4];
    if (EPI >= 1) {
#pragma unroll
      for (int j = 0; j < 4; ++j)
        inv1[j] = (rb + j < M) ? 1.0f / fmaxf((float)cnt1[rb + j], 1.0f) : 1.0f;
    }
    if (EPI == 2) {
#pragma unroll
      for (int j = 0; j < 4; ++j)
        inv2[j] = (rb + j < M) ? 1.0f / fmaxf((float)cnt2[rb + j], 1.0f) : 1.0f;
    }
#pragma unroll
    for (int n = 0; n < 8; ++n) {
      const int col = n * 16 + lr;
#pragma unroll
      for (int j = 0; j < 4; ++j) {
        const int r = rb + j;
        if (r < M) {
          float vv = acc[rg][n][j];
          if (EPI == 0) {
            outB[(size_t)r * DF + col] = f2bf(vv);
          } else if (EPI == 1) {
            float a1 = acc1[(size_t)r * DF + col];
            outF[(size_t)r * DF + col] = fmaxf(vv + a1 * inv1[j], 0.f);
          } else {
            float a1 = acc1[(size_t)r * DF + col];
            float a2 = acc2[(size_t)r * DF + col];
            outF[(size_t)r * DF + col] =
                fmaxf(0.5f * (vv + a1 * inv1[j] + a2 * inv2[j]), 0.f);
          }
        }
      }
    }
  }
}

// ------------- per-edge gather + dropout + f32 scatter-add -----------------
// 16 lanes/edge, 8 features/lane: one 16B bf16 gather, 8 interleaved
// threefrys (ILP block), up to 8 native f32 atomics (skip dropped).
// bits(l) = o0^o1 of threefry(key,(0,l)), l = e*128 + d.
__global__ __launch_bounds__(256) void scatter_f32(
    const ushort_t* __restrict__ proj, const int* __restrict__ src,
    const int* __restrict__ dst, float* __restrict__ accum,
    unsigned* __restrict__ cnt, int E, unsigned k0, unsigned k1) {
  const int t = threadIdx.x;
  const int e = blockIdx.x * 16 + (t >> 4);
  if (e >= E) return;
  const int g16 = t & 15;
  const int d0 = g16 * 8;
  const int s = src[e];
  const int dd = dst[e];
  if (g16 == 0) atomicAdd(&cnt[dd], 1u);

  const uint4 g = *reinterpret_cast<const uint4*>(proj + (size_t)s * DF + d0);
  const unsigned gw[4] = {g.x, g.y, g.z, g.w};
  const unsigned base = (unsigned)e * 128u + (unsigned)d0;

  unsigned bits[8];
#pragma unroll
  for (int j = 0; j < 8; ++j) {
    unsigned o0, o1;
    threefry2x32(k0, k1, 0u, base + j, o0, o1);
    bits[j] = o0 ^ o1;
  }

  float* ap = accum + (size_t)dd * DF + d0;
#pragma unroll
  for (int j = 0; j < 8; ++j) {
    if (bits[j] < KEEP_THR) {
      unsigned u = gw[j >> 1];
      float f = __uint_as_float((j & 1) ? (u & 0xffff0000u) : (u << 16));
      atomicAdd(ap + j, f * (1.0f / 0.9f));
    }
  }
}

// ---------------------------------------------------------------------------
extern "C" void kernel_launch(void* const* d_in, const int* in_sizes, int n_in,
                              void* d_out, int out_size, void* d_ws, size_t ws_size,
                              hipStream_t stream) {
  const float* x_user      = (const float*)d_in[0];
  const float* x_spot      = (const float*)d_in[1];
  const float* W_visit_src = (const float*)d_in[2];
  const float* W_visit_tgt = (const float*)d_in[3];
  const float* W_rev_src   = (const float*)d_in[4];
  const float* W_rev_tgt   = (const float*)d_in[5];
  const float* W_near_src  = (const float*)d_in[6];
  const float* W_near_tgt  = (const float*)d_in[7];
  const int* visit_src = (const int*)d_in[8];
  const int* visit_dst = (const int*)d_in[9];
  const int* rev_src   = (const int*)d_in[10];
  const int* rev_dst   = (const int*)d_in[11];
  const int* near_src  = (const int*)d_in[12];
  const int* near_dst  = (const int*)d_in[13];

  const int n_user = in_sizes[0] / DF;
  const int n_spot = in_sizes[1] / DF;
  const int e_visit = in_sizes[8];
  const int e_rev   = in_sizes[10];
  const int e_near  = in_sizes[12];

  float* out_user = (float*)d_out;
  float* out_spot = out_user + (size_t)n_user * DF;

  // ---- workspace layout (fits 128.8 MB; accum_u overlays dead proj_vs) ----
  // [A] accum_sv  f32  n_spot*DF          (live: scatter-visit .. finalize)
  // [B] accum_u   f32  n_user*DF          (zeroed AFTER scatter-visit)
  //     proj_vs   bf16 n_user*DF  == B    (dead after scatter-visit)
  // [C] proj_rs   bf16 n_spot*DF          (dead after scatter-rev)
  // [D] proj_ns   bf16 n_spot*DF          (dead after scatter-near)
  // [E] accum_sn  f32  n_spot*DF
  // [F] cnt_u, cnt_sv, cnt_sn (contiguous)
  char* ws = (char*)d_ws;
  size_t off = 0;
  auto alloc = [&](size_t bytes) -> void* {
    void* p = ws + off;
    off += (bytes + 255) & ~(size_t)255;
    return p;
  };
  float*    accum_sv = (float*)   alloc((size_t)n_spot * DF * 4);
  float*    accum_u  = (float*)   alloc((size_t)n_user * DF * 4);
  ushort_t* proj_vs  = (ushort_t*)accum_u;
  ushort_t* proj_rs  = (ushort_t*)alloc((size_t)n_spot * DF * 2);
  ushort_t* proj_ns  = (ushort_t*)alloc((size_t)n_spot * DF * 2);
  float*    accum_sn = (float*)   alloc((size_t)n_spot * DF * 4);
  unsigned* cnt_u    = (unsigned*)alloc((size_t)n_user * 4);
  unsigned* cnt_sv   = (unsigned*)alloc((size_t)n_spot * 4);
  unsigned* cnt_sn   = (unsigned*)alloc((size_t)n_spot * 4);
  char* region_end = ws + off;

  // dropout keys: fold_in(key(1), t) == threefry((0,1),(0,t))
  unsigned kv0, kv1, kr0, kr1, kn0, kn1;
  threefry2x32(0u, 1u, 0u, 0u, kv0, kv1);
  threefry2x32(0u, 1u, 0u, 1u, kr0, kr1);
  threefry2x32(0u, 1u, 0u, 2u, kn0, kn1);

  dim3 blk(256);
  const int gb_user = (n_user + 127) / 128;
  const int gb_spot = (n_spot + 127) / 128;

  // source-side projections (bf16 outputs)
  gemm_mfma<0><<<gb_user, blk, 0, stream>>>(x_user, W_visit_src, nullptr, n_user,
                                            proj_vs, nullptr, nullptr, nullptr,
                                            nullptr, nullptr);
  gemm_mfma<0><<<gb_spot, blk, 0, stream>>>(x_spot, W_rev_src, nullptr, n_spot,
                                            proj_rs, nullptr, nullptr, nullptr,
                                            nullptr, nullptr);
  gemm_mfma<0><<<gb_spot, blk, 0, stream>>>(x_spot, W_near_src, nullptr, n_spot,
                                            proj_ns, nullptr, nullptr, nullptr,
                                            nullptr, nullptr);

  // zero accum_sv and the three count arrays
  hipMemsetAsync(accum_sv, 0, (size_t)n_spot * DF * 4, stream);
  hipMemsetAsync(cnt_u, 0, (size_t)(region_end - (char*)cnt_u), stream);

  // visit: user -> spot
  scatter_f32<<<(e_visit + 15) / 16, blk, 0, stream>>>(
      proj_vs, visit_src, visit_dst, accum_sv, cnt_sv, e_visit, kv0, kv1);

  // rev: spot -> user (accum_u overlays proj_vs — zero only after visit)
  hipMemsetAsync(accum_u, 0, (size_t)n_user * DF * 4, stream);
  scatter_f32<<<(e_rev + 15) / 16, blk, 0, stream>>>(
      proj_rs, rev_src, rev_dst, accum_u, cnt_u, e_rev, kr0, kr1);

  // near: spot -> spot
  hipMemsetAsync(accum_sn, 0, (size_t)n_spot * DF * 4, stream);
  scatter_f32<<<(e_near + 15) / 16, blk, 0, stream>>>(
      proj_ns, near_src, near_dst, accum_sn, cnt_sn, e_near, kn0, kn1);

  // finalize: fused tgt-projection + mean + relu
  gemm_mfma<1><<<gb_user, blk, 0, stream>>>(x_user, W_rev_tgt, nullptr, n_user,
                                            nullptr, out_user, accum_u, cnt_u,
                                            nullptr, nullptr);
  gemm_mfma<2><<<gb_spot, blk, 0, stream>>>(x_spot, W_visit_tgt, W_near_tgt, n_spot,
                                            nullptr, out_spot, accum_sv, cnt_sv,
                                            accum_sn, cnt_sn);
}

// Round 4
// 832.340 us; speedup vs baseline: 5.0516x; 5.0516x over previous
//
#include <hip/hip_runtime.h>
#include <stdint.h>

#define DF 128
typedef unsigned short ushort_t;
typedef __attribute__((ext_vector_type(8))) short short8v;   // 8 bf16 (4 VGPRs)
typedef __attribute__((ext_vector_type(4))) float f32x4;

// ---------------- Threefry-2x32 (JAX-compatible, 20 rounds) ----------------
__host__ __device__ __forceinline__ unsigned rotl32(unsigned v, int r) {
  return (v << r) | (v >> (32 - r));
}

__host__ __device__ __forceinline__ void threefry2x32(
    unsigned k0, unsigned k1, unsigned c0, unsigned c1,
    unsigned& o0, unsigned& o1) {
  unsigned kx = k0 ^ k1 ^ 0x1BD11BDAu;
  unsigned x0 = c0 + k0;
  unsigned x1 = c1 + k1;
#define TF_R(r) { x0 += x1; x1 = rotl32(x1, r); x1 ^= x0; }
  TF_R(13) TF_R(15) TF_R(26) TF_R(6)
  x0 += k1; x1 += kx + 1u;
  TF_R(17) TF_R(29) TF_R(16) TF_R(24)
  x0 += kx; x1 += k0 + 2u;
  TF_R(13) TF_R(15) TF_R(26) TF_R(6)
  x0 += k0; x1 += k1 + 3u;
  TF_R(17) TF_R(29) TF_R(16) TF_R(24)
  x0 += k1; x1 += kx + 4u;
  TF_R(13) TF_R(15) TF_R(26) TF_R(6)
  x0 += kx; x1 += k0 + 5u;
#undef TF_R
  o0 = x0; o1 = x1;
}

#define KEEP_THR 0xE6666600u   // uniform(bits) < 0.9f

// ---------------- bf16 helpers (RTNE) --------------------------------------
__device__ __forceinline__ ushort_t f2bf(float f) {
  unsigned u = __float_as_uint(f);
  unsigned r = (u + 0x7fffu + ((u >> 16) & 1u)) >> 16;
  return (ushort_t)r;
}
__device__ __forceinline__ float bf2f(ushort_t h) {
  return __uint_as_float(((unsigned)h) << 16);
}

// ---------------- MFMA GEMM [M,128] x [128,128] ----------------------------
// EPI 0: outB = bf16(X@W1)
// EPI 1: outF = relu(X@W1 + mean1)            (mean1 bf16)
// EPI 2: outF = relu(0.5*(X@(W1+W2) + mean1 + mean2))
template <int EPI>
__global__ __launch_bounds__(256) void gemm_mfma(
    const float* __restrict__ X, const float* __restrict__ W1,
    const float* __restrict__ W2, int M,
    ushort_t* __restrict__ outB, float* __restrict__ outF,
    const ushort_t* __restrict__ m1, const ushort_t* __restrict__ m2) {
  __shared__ ushort_t Wt[DF][136];   // W^T bf16, padded
  const int t = threadIdx.x;
  const int lane = t & 63;
  const int w = t >> 6;
  const int lr = lane & 15;     // A-row / B-col within 16
  const int kg = lane >> 4;     // k-group 0..3
  const int rbase = blockIdx.x * 128;

#pragma unroll
  for (int i = 0; i < 16; ++i) {
    int q = t + i * 256;
    int k = q >> 5;
    int c4 = (q & 31) * 4;
    float4 wv = *reinterpret_cast<const float4*>(&W1[k * DF + c4]);
    if constexpr (EPI == 2) {
      float4 w2 = *reinterpret_cast<const float4*>(&W2[k * DF + c4]);
      wv.x += w2.x; wv.y += w2.y; wv.z += w2.z; wv.w += w2.w;
    }
    Wt[c4 + 0][k] = f2bf(wv.x);
    Wt[c4 + 1][k] = f2bf(wv.y);
    Wt[c4 + 2][k] = f2bf(wv.z);
    Wt[c4 + 3][k] = f2bf(wv.w);
  }
  __syncthreads();

  f32x4 acc[2][8];
#pragma unroll
  for (int rg = 0; rg < 2; ++rg)
#pragma unroll
    for (int n = 0; n < 8; ++n) acc[rg][n] = (f32x4){0.f, 0.f, 0.f, 0.f};

#pragma unroll
  for (int kt = 0; kt < 4; ++kt) {
    const int kb = kt * 32 + kg * 8;
    short8v a[2];
#pragma unroll
    for (int rg = 0; rg < 2; ++rg) {
      int r = rbase + w * 32 + rg * 16 + lr;
      float4 x0 = make_float4(0.f, 0.f, 0.f, 0.f);
      float4 x1 = x0;
      if (r < M) {
        x0 = *reinterpret_cast<const float4*>(&X[(size_t)r * DF + kb]);
        x1 = *reinterpret_cast<const float4*>(&X[(size_t)r * DF + kb + 4]);
      }
      short8v av;
      av[0] = (short)f2bf(x0.x); av[1] = (short)f2bf(x0.y);
      av[2] = (short)f2bf(x0.z); av[3] = (short)f2bf(x0.w);
      av[4] = (short)f2bf(x1.x); av[5] = (short)f2bf(x1.y);
      av[6] = (short)f2bf(x1.z); av[7] = (short)f2bf(x1.w);
      a[rg] = av;
    }
#pragma unroll
    for (int n = 0; n < 8; ++n) {
      short8v b = *reinterpret_cast<const short8v*>(&Wt[n * 16 + lr][kb]);
#pragma unroll
      for (int rg = 0; rg < 2; ++rg)
        acc[rg][n] = __builtin_amdgcn_mfma_f32_16x16x32_bf16(a[rg], b, acc[rg][n], 0, 0, 0);
    }
  }

#pragma unroll
  for (int rg = 0; rg < 2; ++rg) {
    const int rb = rbase + w * 32 + rg * 16 + kg * 4;
#pragma unroll
    for (int n = 0; n < 8; ++n) {
      const int col = n * 16 + lr;
#pragma unroll
      for (int j = 0; j < 4; ++j) {
        const int r = rb + j;
        if (r < M) {
          float vv = acc[rg][n][j];
          if (EPI == 0) {
            outB[(size_t)r * DF + col] = f2bf(vv);
          } else if (EPI == 1) {
            outF[(size_t)r * DF + col] =
                fmaxf(vv + bf2f(m1[(size_t)r * DF + col]), 0.f);
          } else {
            outF[(size_t)r * DF + col] =
                fmaxf(0.5f * (vv + bf2f(m1[(size_t)r * DF + col])
                                 + bf2f(m2[(size_t)r * DF + col])), 0.f);
          }
        }
      }
    }
  }
}

// ---------------- CSR build ------------------------------------------------
__global__ __launch_bounds__(256) void hist3(
    const int* __restrict__ vd, const int* __restrict__ rd,
    const int* __restrict__ nd,
    unsigned* __restrict__ deg_v, unsigned* __restrict__ deg_u,
    unsigned* __restrict__ deg_n, int Ev, int Er, int En) {
  int i = blockIdx.x * 256 + threadIdx.x;
  if (i < Ev) atomicAdd(&deg_v[vd[i]], 1u);
  else if (i < Ev + Er) atomicAdd(&deg_u[rd[i - Ev]], 1u);
  else if (i < Ev + Er + En) atomicAdd(&deg_n[nd[i - Ev - Er]], 1u);
}

// one block per segment: exclusive scan deg -> rowptr (+cursor copy)
__global__ __launch_bounds__(1024) void exscan3(
    const unsigned* __restrict__ deg_v, const unsigned* __restrict__ deg_u,
    const unsigned* __restrict__ deg_n,
    unsigned* __restrict__ rp_v, unsigned* __restrict__ rp_u,
    unsigned* __restrict__ rp_n,
    unsigned* __restrict__ cur_v, unsigned* __restrict__ cur_u,
    unsigned* __restrict__ cur_n, int n_v, int n_u, int n_n) {
  const unsigned* deg; unsigned* rp; unsigned* cur; int n;
  if (blockIdx.x == 0)      { deg = deg_v; rp = rp_v; cur = cur_v; n = n_v; }
  else if (blockIdx.x == 1) { deg = deg_u; rp = rp_u; cur = cur_u; n = n_u; }
  else                      { deg = deg_n; rp = rp_n; cur = cur_n; n = n_n; }
  const int tid = threadIdx.x;
  const int chunk = (n + 1023) / 1024;
  const int lo = tid * chunk;
  const int hi = min(lo + chunk, n);
  unsigned s = 0;
  for (int i = lo; i < hi; ++i) s += deg[i];
  __shared__ unsigned sm[1024];
  sm[tid] = s;
  __syncthreads();
  for (int off = 1; off < 1024; off <<= 1) {
    unsigned v = (tid >= off) ? sm[tid - off] : 0u;
    __syncthreads();
    sm[tid] += v;
    __syncthreads();
  }
  unsigned prefix = sm[tid] - s;   // exclusive prefix at chunk start
  for (int i = lo; i < hi; ++i) {
    rp[i] = prefix;
    cur[i] = prefix;
    prefix += deg[i];
  }
  if (tid == 1023) rp[n] = sm[1023];
}

// fill: es[slot] = (edge_id, src_id) ordered by dst
__global__ __launch_bounds__(256) void fill3(
    const int* __restrict__ vs, const int* __restrict__ vd,
    const int* __restrict__ rs, const int* __restrict__ rd,
    const int* __restrict__ ns, const int* __restrict__ nd,
    unsigned* __restrict__ cur_v, unsigned* __restrict__ cur_u,
    unsigned* __restrict__ cur_n,
    uint2* __restrict__ es_v, uint2* __restrict__ es_r,
    uint2* __restrict__ es_n, int Ev, int Er, int En) {
  int i = blockIdx.x * 256 + threadIdx.x;
  if (i < Ev) {
    unsigned slot = atomicAdd(&cur_v[vd[i]], 1u);
    es_v[slot] = make_uint2((unsigned)i, (unsigned)vs[i]);
  } else if (i < Ev + Er) {
    int e = i - Ev;
    unsigned slot = atomicAdd(&cur_u[rd[e]], 1u);
    es_r[slot] = make_uint2((unsigned)e, (unsigned)rs[e]);
  } else if (i < Ev + Er + En) {
    int e = i - Ev - Er;
    unsigned slot = atomicAdd(&cur_n[nd[e]], 1u);
    es_n[slot] = make_uint2((unsigned)e, (unsigned)ns[e]);
  }
}

// ---------------- gather-reduce: one wave per dst row -----------------------
// lane l accumulates elements 2l,2l+1 in f32 regs over the row's edges;
// dropout mask via threefry(counter = e*128 + d); writes bf16 mean once.
__global__ __launch_bounds__(256) void gather_reduce(
    const ushort_t* __restrict__ proj, const uint2* __restrict__ es,
    const unsigned* __restrict__ rowptr, ushort_t* __restrict__ accum,
    int ndst, unsigned k0, unsigned k1) {
  const int lane = threadIdx.x & 63;
  const int d = blockIdx.x * 4 + (threadIdx.x >> 6);
  if (d >= ndst) return;
  const unsigned b0 = rowptr[d];
  const unsigned n = rowptr[d + 1] - b0;

  float a0 = 0.f, a1 = 0.f;
  uint2 es0 = make_uint2(0u, 0u), es1 = es0;
  unsigned g0 = 0;
  if (n > 0) {
    es0 = es[b0];
    g0 = reinterpret_cast<const unsigned*>(proj + ((size_t)es0.y << 7))[lane];
  }
  if (n > 1) es1 = es[b0 + 1];

  for (unsigned i = 0; i < n; ++i) {
    const unsigned g = g0;
    const unsigned e = es0.x;
    // prefetch: gather for i+1 (src already resolved), indices for i+2
    if (i + 1 < n)
      g0 = reinterpret_cast<const unsigned*>(proj + ((size_t)es1.y << 7))[lane];
    uint2 esn = es1;
    if (i + 2 < n) esn = es[b0 + i + 2];
    es0 = es1; es1 = esn;

    const unsigned c = e * 128u + (unsigned)(lane * 2);
    unsigned r0, r1, q0, q1;
    threefry2x32(k0, k1, 0u, c, r0, r1);
    threefry2x32(k0, k1, 0u, c + 1u, q0, q1);
    const float f0 = __uint_as_float(g << 16);
    const float f1 = __uint_as_float(g & 0xffff0000u);
    a0 += ((r0 ^ r1) < KEEP_THR) ? f0 * (1.0f / 0.9f) : 0.f;
    a1 += ((q0 ^ q1) < KEEP_THR) ? f1 * (1.0f / 0.9f) : 0.f;
  }

  const float inv = 1.0f / fmaxf((float)n, 1.0f);
  const unsigned pk =
      ((unsigned)f2bf(a0 * inv)) | (((unsigned)f2bf(a1 * inv)) << 16);
  reinterpret_cast<unsigned*>(accum)[(size_t)d * 64 + lane] = pk;
}

// ---------------------------------------------------------------------------
extern "C" void kernel_launch(void* const* d_in, const int* in_sizes, int n_in,
                              void* d_out, int out_size, void* d_ws, size_t ws_size,
                              hipStream_t stream) {
  const float* x_user      = (const float*)d_in[0];
  const float* x_spot      = (const float*)d_in[1];
  const float* W_visit_src = (const float*)d_in[2];
  const float* W_visit_tgt = (const float*)d_in[3];
  const float* W_rev_src   = (const float*)d_in[4];
  const float* W_rev_tgt   = (const float*)d_in[5];
  const float* W_near_src  = (const float*)d_in[6];
  const float* W_near_tgt  = (const float*)d_in[7];
  const int* visit_src = (const int*)d_in[8];
  const int* visit_dst = (const int*)d_in[9];
  const int* rev_src   = (const int*)d_in[10];
  const int* rev_dst   = (const int*)d_in[11];
  const int* near_src  = (const int*)d_in[12];
  const int* near_dst  = (const int*)d_in[13];

  const int n_user = in_sizes[0] / DF;
  const int n_spot = in_sizes[1] / DF;
  const int e_visit = in_sizes[8];
  const int e_rev   = in_sizes[10];
  const int e_near  = in_sizes[12];

  float* out_user = (float*)d_out;
  float* out_spot = out_user + (size_t)n_user * DF;

  // ---- workspace (~114 MB, no aliasing) ----
  char* ws = (char*)d_ws;
  size_t off = 0;
  auto alloc = [&](size_t bytes) -> void* {
    void* p = ws + off;
    off += (bytes + 255) & ~(size_t)255;
    return p;
  };
  ushort_t* proj_vs  = (ushort_t*)alloc((size_t)n_user * DF * 2);
  ushort_t* proj_rs  = (ushort_t*)alloc((size_t)n_spot * DF * 2);
  ushort_t* proj_ns  = (ushort_t*)alloc((size_t)n_spot * DF * 2);
  ushort_t* accum_sv = (ushort_t*)alloc((size_t)n_spot * DF * 2);
  ushort_t* accum_u  = (ushort_t*)alloc((size_t)n_user * DF * 2);
  ushort_t* accum_sn = (ushort_t*)alloc((size_t)n_spot * DF * 2);
  uint2*    es_v     = (uint2*)   alloc((size_t)e_visit * 8);
  uint2*    es_r     = (uint2*)   alloc((size_t)e_rev * 8);
  uint2*    es_n     = (uint2*)   alloc((size_t)e_near * 8);
  unsigned* rp_v     = (unsigned*)alloc(((size_t)n_spot + 1) * 4);
  unsigned* rp_u     = (unsigned*)alloc(((size_t)n_user + 1) * 4);
  unsigned* rp_n     = (unsigned*)alloc(((size_t)n_spot + 1) * 4);
  unsigned* cur_v    = (unsigned*)alloc((size_t)n_spot * 4);
  unsigned* cur_u    = (unsigned*)alloc((size_t)n_user * 4);
  unsigned* cur_n    = (unsigned*)alloc((size_t)n_spot * 4);
  unsigned* deg_v    = (unsigned*)alloc((size_t)n_spot * 4);
  unsigned* deg_u    = (unsigned*)alloc((size_t)n_user * 4);
  unsigned* deg_n    = (unsigned*)alloc((size_t)n_spot * 4);
  char* deg_end = ws + off;

  // dropout keys: fold_in(key(1), t) == threefry((0,1),(0,t))
  unsigned kv0, kv1, kr0, kr1, kn0, kn1;
  threefry2x32(0u, 1u, 0u, 0u, kv0, kv1);
  threefry2x32(0u, 1u, 0u, 1u, kr0, kr1);
  threefry2x32(0u, 1u, 0u, 2u, kn0, kn1);

  dim3 blk(256);
  const int gb_user = (n_user + 127) / 128;
  const int gb_spot = (n_spot + 127) / 128;
  const int etot = e_visit + e_rev + e_near;
  const int gb_e = (etot + 255) / 256;

  // CSR build
  hipMemsetAsync(deg_v, 0, (size_t)(deg_end - (char*)deg_v), stream);
  hist3<<<gb_e, blk, 0, stream>>>(visit_dst, rev_dst, near_dst,
                                  deg_v, deg_u, deg_n, e_visit, e_rev, e_near);
  exscan3<<<3, 1024, 0, stream>>>(deg_v, deg_u, deg_n, rp_v, rp_u, rp_n,
                                  cur_v, cur_u, cur_n, n_spot, n_user, n_spot);
  fill3<<<gb_e, blk, 0, stream>>>(visit_src, visit_dst, rev_src, rev_dst,
                                  near_src, near_dst, cur_v, cur_u, cur_n,
                                  es_v, es_r, es_n, e_visit, e_rev, e_near);

  // source-side projections (bf16)
  gemm_mfma<0><<<gb_user, blk, 0, stream>>>(x_user, W_visit_src, nullptr, n_user,
                                            proj_vs, nullptr, nullptr, nullptr);
  gemm_mfma<0><<<gb_spot, blk, 0, stream>>>(x_spot, W_rev_src, nullptr, n_spot,
                                            proj_rs, nullptr, nullptr, nullptr);
  gemm_mfma<0><<<gb_spot, blk, 0, stream>>>(x_spot, W_near_src, nullptr, n_spot,
                                            proj_ns, nullptr, nullptr, nullptr);

  // gather-reduce (writes every row; no accumulator memsets, no f32 atomics)
  gather_reduce<<<(n_spot + 3) / 4, blk, 0, stream>>>(
      proj_vs, es_v, rp_v, accum_sv, n_spot, kv0, kv1);
  gather_reduce<<<(n_user + 3) / 4, blk, 0, stream>>>(
      proj_rs, es_r, rp_u, accum_u, n_user, kr0, kr1);
  gather_reduce<<<(n_spot + 3) / 4, blk, 0, stream>>>(
      proj_ns, es_n, rp_n, accum_sn, n_spot, kn0, kn1);

  // finalize: fused tgt-projection + mean-add + relu
  gemm_mfma<1><<<gb_user, blk, 0, stream>>>(x_user, W_rev_tgt, nullptr, n_user,
                                            nullptr, out_user, accum_u, nullptr);
  gemm_mfma<2><<<gb_spot, blk, 0, stream>>>(x_spot, W_visit_tgt, W_near_tgt, n_spot,
                                            nullptr, out_spot, accum_sv, accum_sn);
}

// Round 5
// 650.985 us; speedup vs baseline: 6.4589x; 1.2786x over previous
//
#include <hip/hip_runtime.h>
#include <stdint.h>

#define DF 128
typedef unsigned short ushort_t;
typedef __attribute__((ext_vector_type(8))) short short8v;   // 8 bf16 (4 VGPRs)
typedef __attribute__((ext_vector_type(4))) float f32x4;

// ---------------- Threefry-2x32 (JAX-compatible, 20 rounds) ----------------
__host__ __device__ __forceinline__ unsigned rotl32(unsigned v, int r) {
#ifdef __HIP_DEVICE_COMPILE__
  return __builtin_amdgcn_alignbit(v, v, 32 - r);   // 1 VALU instr
#else
  return (v << r) | (v >> (32 - r));
#endif
}

__host__ __device__ __forceinline__ void threefry2x32(
    unsigned k0, unsigned k1, unsigned c0, unsigned c1,
    unsigned& o0, unsigned& o1) {
  unsigned kx = k0 ^ k1 ^ 0x1BD11BDAu;
  unsigned x0 = c0 + k0;
  unsigned x1 = c1 + k1;
#define TF_R(r) { x0 += x1; x1 = rotl32(x1, r); x1 ^= x0; }
  TF_R(13) TF_R(15) TF_R(26) TF_R(6)
  x0 += k1; x1 += kx + 1u;
  TF_R(17) TF_R(29) TF_R(16) TF_R(24)
  x0 += kx; x1 += k0 + 2u;
  TF_R(13) TF_R(15) TF_R(26) TF_R(6)
  x0 += k0; x1 += k1 + 3u;
  TF_R(17) TF_R(29) TF_R(16) TF_R(24)
  x0 += k1; x1 += kx + 4u;
  TF_R(13) TF_R(15) TF_R(26) TF_R(6)
  x0 += kx; x1 += k0 + 5u;
#undef TF_R
  o0 = x0; o1 = x1;
}

#define KEEP_THR 0xE6666600u   // uniform(bits) < 0.9f

// ---------------- bf16 helpers (RTNE) --------------------------------------
__device__ __forceinline__ ushort_t f2bf(float f) {
  unsigned u = __float_as_uint(f);
  unsigned r = (u + 0x7fffu + ((u >> 16) & 1u)) >> 16;
  return (ushort_t)r;
}
__device__ __forceinline__ float bf2f(ushort_t h) {
  return __uint_as_float(((unsigned)h) << 16);
}

// ---------------- MFMA GEMM [M,128] x [128,128] ----------------------------
// EPI 0: outB = bf16(X@W1)
// EPI 1: outF = relu(X@W1 + mean1)            (mean1 bf16)
// EPI 2: outF = relu(0.5*(X@(W1+W2) + mean1 + mean2))
template <int EPI>
__global__ __launch_bounds__(256) void gemm_mfma(
    const float* __restrict__ X, const float* __restrict__ W1,
    const float* __restrict__ W2, int M,
    ushort_t* __restrict__ outB, float* __restrict__ outF,
    const ushort_t* __restrict__ m1, const ushort_t* __restrict__ m2) {
  __shared__ ushort_t Wt[DF][136];   // W^T bf16, padded
  const int t = threadIdx.x;
  const int lane = t & 63;
  const int w = t >> 6;
  const int lr = lane & 15;     // A-row / B-col within 16
  const int kg = lane >> 4;     // k-group 0..3
  const int rbase = blockIdx.x * 128;

#pragma unroll
  for (int i = 0; i < 16; ++i) {
    int q = t + i * 256;
    int k = q >> 5;
    int c4 = (q & 31) * 4;
    float4 wv = *reinterpret_cast<const float4*>(&W1[k * DF + c4]);
    if constexpr (EPI == 2) {
      float4 w2 = *reinterpret_cast<const float4*>(&W2[k * DF + c4]);
      wv.x += w2.x; wv.y += w2.y; wv.z += w2.z; wv.w += w2.w;
    }
    Wt[c4 + 0][k] = f2bf(wv.x);
    Wt[c4 + 1][k] = f2bf(wv.y);
    Wt[c4 + 2][k] = f2bf(wv.z);
    Wt[c4 + 3][k] = f2bf(wv.w);
  }
  __syncthreads();

  f32x4 acc[2][8];
#pragma unroll
  for (int rg = 0; rg < 2; ++rg)
#pragma unroll
    for (int n = 0; n < 8; ++n) acc[rg][n] = (f32x4){0.f, 0.f, 0.f, 0.f};

#pragma unroll
  for (int kt = 0; kt < 4; ++kt) {
    const int kb = kt * 32 + kg * 8;
    short8v a[2];
#pragma unroll
    for (int rg = 0; rg < 2; ++rg) {
      int r = rbase + w * 32 + rg * 16 + lr;
      float4 x0 = make_float4(0.f, 0.f, 0.f, 0.f);
      float4 x1 = x0;
      if (r < M) {
        x0 = *reinterpret_cast<const float4*>(&X[(size_t)r * DF + kb]);
        x1 = *reinterpret_cast<const float4*>(&X[(size_t)r * DF + kb + 4]);
      }
      short8v av;
      av[0] = (short)f2bf(x0.x); av[1] = (short)f2bf(x0.y);
      av[2] = (short)f2bf(x0.z); av[3] = (short)f2bf(x0.w);
      av[4] = (short)f2bf(x1.x); av[5] = (short)f2bf(x1.y);
      av[6] = (short)f2bf(x1.z); av[7] = (short)f2bf(x1.w);
      a[rg] = av;
    }
#pragma unroll
    for (int n = 0; n < 8; ++n) {
      short8v b = *reinterpret_cast<const short8v*>(&Wt[n * 16 + lr][kb]);
#pragma unroll
      for (int rg = 0; rg < 2; ++rg)
        acc[rg][n] = __builtin_amdgcn_mfma_f32_16x16x32_bf16(a[rg], b, acc[rg][n], 0, 0, 0);
    }
  }

#pragma unroll
  for (int rg = 0; rg < 2; ++rg) {
    const int rb = rbase + w * 32 + rg * 16 + kg * 4;
#pragma unroll
    for (int n = 0; n < 8; ++n) {
      const int col = n * 16 + lr;
#pragma unroll
      for (int j = 0; j < 4; ++j) {
        const int r = rb + j;
        if (r < M) {
          float vv = acc[rg][n][j];
          if (EPI == 0) {
            outB[(size_t)r * DF + col] = f2bf(vv);
          } else if (EPI == 1) {
            outF[(size_t)r * DF + col] =
                fmaxf(vv + bf2f(m1[(size_t)r * DF + col]), 0.f);
          } else {
            outF[(size_t)r * DF + col] =
                fmaxf(0.5f * (vv + bf2f(m1[(size_t)r * DF + col])
                                 + bf2f(m2[(size_t)r * DF + col])), 0.f);
          }
        }
      }
    }
  }
}

// ---------------- CSR build (unified: segments concatenated) ---------------
// deg_all rows: [0,n_spot) visit-dst | [n_spot,+n_user) rev-dst | [..,+n_spot) near-dst
__global__ __launch_bounds__(256) void hist3(
    const int* __restrict__ vd, const int* __restrict__ rd,
    const int* __restrict__ nd, unsigned* __restrict__ deg_all,
    int Ev, int Er, int En, int segU, int segN) {
  int i = blockIdx.x * 256 + threadIdx.x;
  if (i < Ev) atomicAdd(&deg_all[vd[i]], 1u);
  else if (i < Ev + Er) atomicAdd(&deg_all[segU + rd[i - Ev]], 1u);
  else if (i < Ev + Er + En) atomicAdd(&deg_all[segN + nd[i - Ev - Er]], 1u);
}

// ---- 2-level exclusive scan over deg_all[NT] -> rp_all/cur_all -------------
#define SCAN_E 2048   // 256 threads x 8 elems

__global__ __launch_bounds__(256) void scanA(
    const unsigned* __restrict__ deg, unsigned* __restrict__ bsum, int NT) {
  __shared__ unsigned sm[256];
  const int t = threadIdx.x;
  const int base = blockIdx.x * SCAN_E + t * 8;
  unsigned s = 0;
#pragma unroll
  for (int j = 0; j < 8; ++j) {
    int i = base + j;
    s += (i < NT) ? deg[i] : 0u;
  }
  sm[t] = s;
  __syncthreads();
  for (int off = 128; off; off >>= 1) {
    if (t < off) sm[t] += sm[t + off];
    __syncthreads();
  }
  if (t == 0) bsum[blockIdx.x] = sm[0];
}

__global__ __launch_bounds__(1024) void scanB(
    unsigned* __restrict__ bsum, unsigned* __restrict__ rp_all,
    int nb, int NT) {
  __shared__ unsigned sm[1024];
  const int t = threadIdx.x;
  unsigned v = (t < nb) ? bsum[t] : 0u;
  sm[t] = v;
  __syncthreads();
  for (int off = 1; off < 1024; off <<= 1) {
    unsigned u = (t >= off) ? sm[t - off] : 0u;
    __syncthreads();
    sm[t] += u;
    __syncthreads();
  }
  if (t < nb) bsum[t] = sm[t] - v;            // exclusive
  if (t == nb - 1) rp_all[NT] = sm[t];        // grand total
}

__global__ __launch_bounds__(256) void scanC(
    const unsigned* __restrict__ deg, const unsigned* __restrict__ bsum,
    unsigned* __restrict__ rp, unsigned* __restrict__ cur, int NT) {
  __shared__ unsigned sm[256];
  const int t = threadIdx.x;
  const int base = blockIdx.x * SCAN_E + t * 8;
  unsigned vals[8];
  unsigned s = 0;
#pragma unroll
  for (int j = 0; j < 8; ++j) {
    int i = base + j;
    vals[j] = (i < NT) ? deg[i] : 0u;
    s += vals[j];
  }
  sm[t] = s;
  __syncthreads();
  for (int off = 1; off < 256; off <<= 1) {
    unsigned u = (t >= off) ? sm[t - off] : 0u;
    __syncthreads();
    sm[t] += u;
    __syncthreads();
  }
  unsigned run = bsum[blockIdx.x] + sm[t] - s;  // exclusive at this thread
#pragma unroll
  for (int j = 0; j < 8; ++j) {
    int i = base + j;
    if (i < NT) { rp[i] = run; cur[i] = run; }
    run += vals[j];
  }
}

// fill: es_all[slot] = (edge_id, src_id), slots global across segments
__global__ __launch_bounds__(256) void fill3(
    const int* __restrict__ vs, const int* __restrict__ vd,
    const int* __restrict__ rs, const int* __restrict__ rd,
    const int* __restrict__ ns, const int* __restrict__ nd,
    unsigned* __restrict__ cur_all, uint2* __restrict__ es_all,
    int Ev, int Er, int En, int segU, int segN) {
  int i = blockIdx.x * 256 + threadIdx.x;
  if (i < Ev) {
    unsigned slot = atomicAdd(&cur_all[vd[i]], 1u);
    es_all[slot] = make_uint2((unsigned)i, (unsigned)vs[i]);
  } else if (i < Ev + Er) {
    int e = i - Ev;
    unsigned slot = atomicAdd(&cur_all[segU + rd[e]], 1u);
    es_all[slot] = make_uint2((unsigned)e, (unsigned)rs[e]);
  } else if (i < Ev + Er + En) {
    int e = i - Ev - Er;
    unsigned slot = atomicAdd(&cur_all[segN + nd[e]], 1u);
    es_all[slot] = make_uint2((unsigned)e, (unsigned)ns[e]);
  }
}

// ---------------- gather-reduce: one wave per dst row -----------------------
__global__ __launch_bounds__(256) void gather_reduce(
    const ushort_t* __restrict__ proj, const uint2* __restrict__ es,
    const unsigned* __restrict__ rowptr, ushort_t* __restrict__ accum,
    int ndst, unsigned k0, unsigned k1) {
  const int lane = threadIdx.x & 63;
  const int d = blockIdx.x * 4 + (threadIdx.x >> 6);
  if (d >= ndst) return;
  const unsigned b0 = rowptr[d];
  const unsigned n = rowptr[d + 1] - b0;

  float a0 = 0.f, a1 = 0.f;
  uint2 es0 = make_uint2(0u, 0u), es1 = es0;
  unsigned g0 = 0;
  if (n > 0) {
    es0 = es[b0];
    g0 = reinterpret_cast<const unsigned*>(proj + ((size_t)es0.y << 7))[lane];
  }
  if (n > 1) es1 = es[b0 + 1];

  for (unsigned i = 0; i < n; ++i) {
    const unsigned g = g0;
    const unsigned e = es0.x;
    if (i + 1 < n)
      g0 = reinterpret_cast<const unsigned*>(proj + ((size_t)es1.y << 7))[lane];
    uint2 esn = es1;
    if (i + 2 < n) esn = es[b0 + i + 2];
    es0 = es1; es1 = esn;

    const unsigned c = e * 128u + (unsigned)(lane * 2);
    unsigned r0, r1, q0, q1;
    threefry2x32(k0, k1, 0u, c, r0, r1);
    threefry2x32(k0, k1, 0u, c + 1u, q0, q1);
    const float f0 = __uint_as_float(g << 16);
    const float f1 = __uint_as_float(g & 0xffff0000u);
    a0 += ((r0 ^ r1) < KEEP_THR) ? f0 * (1.0f / 0.9f) : 0.f;
    a1 += ((q0 ^ q1) < KEEP_THR) ? f1 * (1.0f / 0.9f) : 0.f;
  }

  const float inv = 1.0f / fmaxf((float)n, 1.0f);
  const unsigned pk =
      ((unsigned)f2bf(a0 * inv)) | (((unsigned)f2bf(a1 * inv)) << 16);
  reinterpret_cast<unsigned*>(accum)[(size_t)d * 64 + lane] = pk;
}

// ---------------------------------------------------------------------------
extern "C" void kernel_launch(void* const* d_in, const int* in_sizes, int n_in,
                              void* d_out, int out_size, void* d_ws, size_t ws_size,
                              hipStream_t stream) {
  const float* x_user      = (const float*)d_in[0];
  const float* x_spot      = (const float*)d_in[1];
  const float* W_visit_src = (const float*)d_in[2];
  const float* W_visit_tgt = (const float*)d_in[3];
  const float* W_rev_src   = (const float*)d_in[4];
  const float* W_rev_tgt   = (const float*)d_in[5];
  const float* W_near_src  = (const float*)d_in[6];
  const float* W_near_tgt  = (const float*)d_in[7];
  const int* visit_src = (const int*)d_in[8];
  const int* visit_dst = (const int*)d_in[9];
  const int* rev_src   = (const int*)d_in[10];
  const int* rev_dst   = (const int*)d_in[11];
  const int* near_src  = (const int*)d_in[12];
  const int* near_dst  = (const int*)d_in[13];

  const int n_user = in_sizes[0] / DF;
  const int n_spot = in_sizes[1] / DF;
  const int e_visit = in_sizes[8];
  const int e_rev   = in_sizes[10];
  const int e_near  = in_sizes[12];

  float* out_user = (float*)d_out;
  float* out_spot = out_user + (size_t)n_user * DF;

  const int NT = n_spot + n_user + n_spot;       // unified row count
  const int segU = n_spot;
  const int segN = n_spot + n_user;
  const int etot = e_visit + e_rev + e_near;

  // ---- workspace ----
  char* ws = (char*)d_ws;
  size_t off = 0;
  auto alloc = [&](size_t bytes) -> void* {
    void* p = ws + off;
    off += (bytes + 255) & ~(size_t)255;
    return p;
  };
  ushort_t* proj_vs  = (ushort_t*)alloc((size_t)n_user * DF * 2);
  ushort_t* proj_rs  = (ushort_t*)alloc((size_t)n_spot * DF * 2);
  ushort_t* proj_ns  = (ushort_t*)alloc((size_t)n_spot * DF * 2);
  ushort_t* accum_sv = (ushort_t*)alloc((size_t)n_spot * DF * 2);
  ushort_t* accum_u  = (ushort_t*)alloc((size_t)n_user * DF * 2);
  ushort_t* accum_sn = (ushort_t*)alloc((size_t)n_spot * DF * 2);
  uint2*    es_all   = (uint2*)   alloc((size_t)etot * 8);
  unsigned* rp_all   = (unsigned*)alloc(((size_t)NT + 1) * 4);
  unsigned* cur_all  = (unsigned*)alloc((size_t)NT * 4);
  unsigned* deg_all  = (unsigned*)alloc((size_t)NT * 4);
  unsigned* bsum     = (unsigned*)alloc(4096);

  // dropout keys: fold_in(key(1), t) == threefry((0,1),(0,t))
  unsigned kv0, kv1, kr0, kr1, kn0, kn1;
  threefry2x32(0u, 1u, 0u, 0u, kv0, kv1);
  threefry2x32(0u, 1u, 0u, 1u, kr0, kr1);
  threefry2x32(0u, 1u, 0u, 2u, kn0, kn1);

  dim3 blk(256);
  const int gb_user = (n_user + 127) / 128;
  const int gb_spot = (n_spot + 127) / 128;
  const int gb_e = (etot + 255) / 256;
  const int nb_scan = (NT + SCAN_E - 1) / SCAN_E;

  // CSR build (unified)
  hipMemsetAsync(deg_all, 0, (size_t)NT * 4, stream);
  hist3<<<gb_e, blk, 0, stream>>>(visit_dst, rev_dst, near_dst, deg_all,
                                  e_visit, e_rev, e_near, segU, segN);
  scanA<<<nb_scan, blk, 0, stream>>>(deg_all, bsum, NT);
  scanB<<<1, 1024, 0, stream>>>(bsum, rp_all, nb_scan, NT);
  scanC<<<nb_scan, blk, 0, stream>>>(deg_all, bsum, rp_all, cur_all, NT);
  fill3<<<gb_e, blk, 0, stream>>>(visit_src, visit_dst, rev_src, rev_dst,
                                  near_src, near_dst, cur_all, es_all,
                                  e_visit, e_rev, e_near, segU, segN);

  // source-side projections (bf16)
  gemm_mfma<0><<<gb_user, blk, 0, stream>>>(x_user, W_visit_src, nullptr, n_user,
                                            proj_vs, nullptr, nullptr, nullptr);
  gemm_mfma<0><<<gb_spot, blk, 0, stream>>>(x_spot, W_rev_src, nullptr, n_spot,
                                            proj_rs, nullptr, nullptr, nullptr);
  gemm_mfma<0><<<gb_spot, blk, 0, stream>>>(x_spot, W_near_src, nullptr, n_spot,
                                            proj_ns, nullptr, nullptr, nullptr);

  // gather-reduce (rowptr offset by segment base; es slots are global)
  gather_reduce<<<(n_spot + 3) / 4, blk, 0, stream>>>(
      proj_vs, es_all, rp_all, accum_sv, n_spot, kv0, kv1);
  gather_reduce<<<(n_user + 3) / 4, blk, 0, stream>>>(
      proj_rs, es_all, rp_all + segU, accum_u, n_user, kr0, kr1);
  gather_reduce<<<(n_spot + 3) / 4, blk, 0, stream>>>(
      proj_ns, es_all, rp_all + segN, accum_sn, n_spot, kn0, kn1);

  // finalize: fused tgt-projection + mean-add + relu
  gemm_mfma<1><<<gb_user, blk, 0, stream>>>(x_user, W_rev_tgt, nullptr, n_user,
                                            nullptr, out_user, accum_u, nullptr);
  gemm_mfma<2><<<gb_spot, blk, 0, stream>>>(x_spot, W_visit_tgt, W_near_tgt, n_spot,
                                            nullptr, out_spot, accum_sv, accum_sn);
}

// Round 6
// 616.909 us; speedup vs baseline: 6.8157x; 1.0552x over previous
//
#include <hip/hip_runtime.h>
#include <stdint.h>

#define DF 128
typedef unsigned short ushort_t;
typedef __attribute__((ext_vector_type(8))) short short8v;   // 8 bf16 (4 VGPRs)
typedef __attribute__((ext_vector_type(4))) float f32x4;

// ---------------- Threefry-2x32 (JAX-compatible, 20 rounds) ----------------
__host__ __device__ __forceinline__ unsigned rotl32(unsigned v, int r) {
  return __builtin_rotateleft32(v, (unsigned)r);   // fshl -> v_alignbit_b32
}

__host__ __device__ __forceinline__ void threefry2x32(
    unsigned k0, unsigned k1, unsigned c0, unsigned c1,
    unsigned& o0, unsigned& o1) {
  unsigned kx = k0 ^ k1 ^ 0x1BD11BDAu;
  unsigned x0 = c0 + k0;
  unsigned x1 = c1 + k1;
#define TF_R(r) { x0 += x1; x1 = rotl32(x1, r); x1 ^= x0; }
  TF_R(13) TF_R(15) TF_R(26) TF_R(6)
  x0 += k1; x1 += kx + 1u;
  TF_R(17) TF_R(29) TF_R(16) TF_R(24)
  x0 += kx; x1 += k0 + 2u;
  TF_R(13) TF_R(15) TF_R(26) TF_R(6)
  x0 += k0; x1 += k1 + 3u;
  TF_R(17) TF_R(29) TF_R(16) TF_R(24)
  x0 += k1; x1 += kx + 4u;
  TF_R(13) TF_R(15) TF_R(26) TF_R(6)
  x0 += kx; x1 += k0 + 5u;
#undef TF_R
  o0 = x0; o1 = x1;
}

#define KEEP_THR 0xE6666600u   // uniform(bits) < 0.9f

// ---------------- bf16 helpers (RTNE) --------------------------------------
__device__ __forceinline__ ushort_t f2bf(float f) {
  unsigned u = __float_as_uint(f);
  unsigned r = (u + 0x7fffu + ((u >> 16) & 1u)) >> 16;
  return (ushort_t)r;
}
__device__ __forceinline__ float bf2f(ushort_t h) {
  return __uint_as_float(((unsigned)h) << 16);
}

// ---------------- MFMA GEMM [M,128] x [128,128] ----------------------------
// EPI 0: outB = bf16(X@W1)
// EPI 1: outF = relu(X@W1 + mean1)            (mean1 bf16)
// EPI 2: outF = relu(0.5*(X@(W1+W2) + mean1 + mean2))
template <int EPI>
__global__ __launch_bounds__(256) void gemm_mfma(
    const float* __restrict__ X, const float* __restrict__ W1,
    const float* __restrict__ W2, int M,
    ushort_t* __restrict__ outB, float* __restrict__ outF,
    const ushort_t* __restrict__ m1, const ushort_t* __restrict__ m2) {
  __shared__ ushort_t Wt[DF][136];   // W^T bf16, padded
  const int t = threadIdx.x;
  const int lane = t & 63;
  const int w = t >> 6;
  const int lr = lane & 15;     // A-row / B-col within 16
  const int kg = lane >> 4;     // k-group 0..3
  const int rbase = blockIdx.x * 128;

#pragma unroll
  for (int i = 0; i < 16; ++i) {
    int q = t + i * 256;
    int k = q >> 5;
    int c4 = (q & 31) * 4;
    float4 wv = *reinterpret_cast<const float4*>(&W1[k * DF + c4]);
    if constexpr (EPI == 2) {
      float4 w2 = *reinterpret_cast<const float4*>(&W2[k * DF + c4]);
      wv.x += w2.x; wv.y += w2.y; wv.z += w2.z; wv.w += w2.w;
    }
    Wt[c4 + 0][k] = f2bf(wv.x);
    Wt[c4 + 1][k] = f2bf(wv.y);
    Wt[c4 + 2][k] = f2bf(wv.z);
    Wt[c4 + 3][k] = f2bf(wv.w);
  }
  __syncthreads();

  f32x4 acc[2][8];
#pragma unroll
  for (int rg = 0; rg < 2; ++rg)
#pragma unroll
    for (int n = 0; n < 8; ++n) acc[rg][n] = (f32x4){0.f, 0.f, 0.f, 0.f};

#pragma unroll
  for (int kt = 0; kt < 4; ++kt) {
    const int kb = kt * 32 + kg * 8;
    short8v a[2];
#pragma unroll
    for (int rg = 0; rg < 2; ++rg) {
      int r = rbase + w * 32 + rg * 16 + lr;
      float4 x0 = make_float4(0.f, 0.f, 0.f, 0.f);
      float4 x1 = x0;
      if (r < M) {
        x0 = *reinterpret_cast<const float4*>(&X[(size_t)r * DF + kb]);
        x1 = *reinterpret_cast<const float4*>(&X[(size_t)r * DF + kb + 4]);
      }
      short8v av;
      av[0] = (short)f2bf(x0.x); av[1] = (short)f2bf(x0.y);
      av[2] = (short)f2bf(x0.z); av[3] = (short)f2bf(x0.w);
      av[4] = (short)f2bf(x1.x); av[5] = (short)f2bf(x1.y);
      av[6] = (short)f2bf(x1.z); av[7] = (short)f2bf(x1.w);
      a[rg] = av;
    }
#pragma unroll
    for (int n = 0; n < 8; ++n) {
      short8v b = *reinterpret_cast<const short8v*>(&Wt[n * 16 + lr][kb]);
#pragma unroll
      for (int rg = 0; rg < 2; ++rg)
        acc[rg][n] = __builtin_amdgcn_mfma_f32_16x16x32_bf16(a[rg], b, acc[rg][n], 0, 0, 0);
    }
  }

#pragma unroll
  for (int rg = 0; rg < 2; ++rg) {
    const int rb = rbase + w * 32 + rg * 16 + kg * 4;
#pragma unroll
    for (int n = 0; n < 8; ++n) {
      const int col = n * 16 + lr;
#pragma unroll
      for (int j = 0; j < 4; ++j) {
        const int r = rb + j;
        if (r < M) {
          float vv = acc[rg][n][j];
          if (EPI == 0) {
            outB[(size_t)r * DF + col] = f2bf(vv);
          } else if (EPI == 1) {
            outF[(size_t)r * DF + col] =
                fmaxf(vv + bf2f(m1[(size_t)r * DF + col]), 0.f);
          } else {
            outF[(size_t)r * DF + col] =
                fmaxf(0.5f * (vv + bf2f(m1[(size_t)r * DF + col])
                                 + bf2f(m2[(size_t)r * DF + col])), 0.f);
          }
        }
      }
    }
  }
}

// ---------------- CSR build (unified: segments concatenated) ---------------
__global__ __launch_bounds__(256) void hist3(
    const int* __restrict__ vd, const int* __restrict__ rd,
    const int* __restrict__ nd, unsigned* __restrict__ deg_all,
    int Ev, int Er, int En, int segU, int segN) {
  int i = blockIdx.x * 256 + threadIdx.x;
  if (i < Ev) atomicAdd(&deg_all[vd[i]], 1u);
  else if (i < Ev + Er) atomicAdd(&deg_all[segU + rd[i - Ev]], 1u);
  else if (i < Ev + Er + En) atomicAdd(&deg_all[segN + nd[i - Ev - Er]], 1u);
}

// ---- 2-level exclusive scan over deg_all[NT] -> rp_all/cur_all -------------
#define SCAN_E 2048   // 256 threads x 8 elems

__global__ __launch_bounds__(256) void scanA(
    const unsigned* __restrict__ deg, unsigned* __restrict__ bsum, int NT) {
  __shared__ unsigned sm[256];
  const int t = threadIdx.x;
  const int base = blockIdx.x * SCAN_E + t * 8;
  unsigned s = 0;
#pragma unroll
  for (int j = 0; j < 8; ++j) {
    int i = base + j;
    s += (i < NT) ? deg[i] : 0u;
  }
  sm[t] = s;
  __syncthreads();
  for (int off = 128; off; off >>= 1) {
    if (t < off) sm[t] += sm[t + off];
    __syncthreads();
  }
  if (t == 0) bsum[blockIdx.x] = sm[0];
}

__global__ __launch_bounds__(1024) void scanB(
    unsigned* __restrict__ bsum, unsigned* __restrict__ rp_all,
    int nb, int NT) {
  __shared__ unsigned sm[1024];
  const int t = threadIdx.x;
  unsigned v = (t < nb) ? bsum[t] : 0u;
  sm[t] = v;
  __syncthreads();
  for (int off = 1; off < 1024; off <<= 1) {
    unsigned u = (t >= off) ? sm[t - off] : 0u;
    __syncthreads();
    sm[t] += u;
    __syncthreads();
  }
  if (t < nb) bsum[t] = sm[t] - v;            // exclusive
  if (t == nb - 1) rp_all[NT] = sm[t];        // grand total
}

__global__ __launch_bounds__(256) void scanC(
    const unsigned* __restrict__ deg, const unsigned* __restrict__ bsum,
    unsigned* __restrict__ rp, unsigned* __restrict__ cur, int NT) {
  __shared__ unsigned sm[256];
  const int t = threadIdx.x;
  const int base = blockIdx.x * SCAN_E + t * 8;
  unsigned vals[8];
  unsigned s = 0;
#pragma unroll
  for (int j = 0; j < 8; ++j) {
    int i = base + j;
    vals[j] = (i < NT) ? deg[i] : 0u;
    s += vals[j];
  }
  sm[t] = s;
  __syncthreads();
  for (int off = 1; off < 256; off <<= 1) {
    unsigned u = (t >= off) ? sm[t - off] : 0u;
    __syncthreads();
    sm[t] += u;
    __syncthreads();
  }
  unsigned run = bsum[blockIdx.x] + sm[t] - s;  // exclusive at this thread
#pragma unroll
  for (int j = 0; j < 8; ++j) {
    int i = base + j;
    if (i < NT) { rp[i] = run; cur[i] = run; }
    run += vals[j];
  }
}

// fill: es_all[slot] = (edge_id, src_id), slots global across segments
__global__ __launch_bounds__(256) void fill3(
    const int* __restrict__ vs, const int* __restrict__ vd,
    const int* __restrict__ rs, const int* __restrict__ rd,
    const int* __restrict__ ns, const int* __restrict__ nd,
    unsigned* __restrict__ cur_all, uint2* __restrict__ es_all,
    int Ev, int Er, int En, int segU, int segN) {
  int i = blockIdx.x * 256 + threadIdx.x;
  if (i < Ev) {
    unsigned slot = atomicAdd(&cur_all[vd[i]], 1u);
    es_all[slot] = make_uint2((unsigned)i, (unsigned)vs[i]);
  } else if (i < Ev + Er) {
    int e = i - Ev;
    unsigned slot = atomicAdd(&cur_all[segU + rd[e]], 1u);
    es_all[slot] = make_uint2((unsigned)e, (unsigned)rs[e]);
  } else if (i < Ev + Er + En) {
    int e = i - Ev - Er;
    unsigned slot = atomicAdd(&cur_all[segN + nd[e]], 1u);
    es_all[slot] = make_uint2((unsigned)e, (unsigned)ns[e]);
  }
}

// ---------------- gather-reduce: one wave per dst row (scalarized) ----------
// All control (row ptrs, es entries, edge ids, loop bounds) forced to SGPRs:
// es loads become s_load, gather address is scalar-base + lane offset.
// Unconditional clamped prefetch (2-deep) — no per-iter exec-mask juggling.
__global__ __launch_bounds__(256) void gather_reduce(
    const ushort_t* __restrict__ proj, const uint2* __restrict__ es,
    const unsigned* __restrict__ rowptr, ushort_t* __restrict__ accum,
    int ndst, unsigned emax, unsigned k0, unsigned k1) {
  const int lane = threadIdx.x & 63;
  int d = blockIdx.x * 4 + (threadIdx.x >> 6);
  d = __builtin_amdgcn_readfirstlane(d);     // whole wave shares d
  if (d >= ndst) return;
  const unsigned b0 = __builtin_amdgcn_readfirstlane(rowptr[d]);
  const unsigned n  = __builtin_amdgcn_readfirstlane(rowptr[d + 1]) - b0;

  const unsigned lane2 = (unsigned)lane * 2u;

  // 2-deep scalar pipeline, indices clamped to valid range (values ignored
  // when past the row end — loop trip count is n).
  uint2 e0 = es[min(b0, emax)];
  uint2 e1 = es[min(b0 + 1u, emax)];
  unsigned g0 =
      reinterpret_cast<const unsigned*>(proj + ((size_t)e0.y << 7))[lane];

  float a0 = 0.f, a1 = 0.f;
  for (unsigned i = 0; i < n; ++i) {
    const unsigned g = g0;
    const unsigned eid = e0.x;
    // prefetch next gather + es two ahead (unconditional, clamped)
    g0 = reinterpret_cast<const unsigned*>(proj + ((size_t)e1.y << 7))[lane];
    e0 = e1;
    e1 = es[min(b0 + i + 2u, emax)];

    const unsigned cb = eid * 128u + lane2;   // eid SGPR -> SALU mul
    unsigned r0, r1, q0, q1;
    threefry2x32(k0, k1, 0u, cb, r0, r1);
    threefry2x32(k0, k1, 0u, cb + 1u, q0, q1);
    const float m0 = ((r0 ^ r1) < KEEP_THR) ? (1.0f / 0.9f) : 0.f;
    const float m1 = ((q0 ^ q1) < KEEP_THR) ? (1.0f / 0.9f) : 0.f;
    a0 = fmaf(__uint_as_float(g << 16), m0, a0);
    a1 = fmaf(__uint_as_float(g & 0xffff0000u), m1, a1);
  }

  const float inv = 1.0f / fmaxf((float)n, 1.0f);
  const unsigned pk =
      ((unsigned)f2bf(a0 * inv)) | (((unsigned)f2bf(a1 * inv)) << 16);
  reinterpret_cast<unsigned*>(accum)[(size_t)d * 64 + lane] = pk;
}

// ---------------------------------------------------------------------------
extern "C" void kernel_launch(void* const* d_in, const int* in_sizes, int n_in,
                              void* d_out, int out_size, void* d_ws, size_t ws_size,
                              hipStream_t stream) {
  const float* x_user      = (const float*)d_in[0];
  const float* x_spot      = (const float*)d_in[1];
  const float* W_visit_src = (const float*)d_in[2];
  const float* W_visit_tgt = (const float*)d_in[3];
  const float* W_rev_src   = (const float*)d_in[4];
  const float* W_rev_tgt   = (const float*)d_in[5];
  const float* W_near_src  = (const float*)d_in[6];
  const float* W_near_tgt  = (const float*)d_in[7];
  const int* visit_src = (const int*)d_in[8];
  const int* visit_dst = (const int*)d_in[9];
  const int* rev_src   = (const int*)d_in[10];
  const int* rev_dst   = (const int*)d_in[11];
  const int* near_src  = (const int*)d_in[12];
  const int* near_dst  = (const int*)d_in[13];

  const int n_user = in_sizes[0] / DF;
  const int n_spot = in_sizes[1] / DF;
  const int e_visit = in_sizes[8];
  const int e_rev   = in_sizes[10];
  const int e_near  = in_sizes[12];

  float* out_user = (float*)d_out;
  float* out_spot = out_user + (size_t)n_user * DF;

  const int NT = n_spot + n_user + n_spot;       // unified row count
  const int segU = n_spot;
  const int segN = n_spot + n_user;
  const int etot = e_visit + e_rev + e_near;
  const unsigned emax = (unsigned)(etot - 1);

  // ---- workspace ----
  char* ws = (char*)d_ws;
  size_t off = 0;
  auto alloc = [&](size_t bytes) -> void* {
    void* p = ws + off;
    off += (bytes + 255) & ~(size_t)255;
    return p;
  };
  ushort_t* proj_vs  = (ushort_t*)alloc((size_t)n_user * DF * 2);
  ushort_t* proj_rs  = (ushort_t*)alloc((size_t)n_spot * DF * 2);
  ushort_t* proj_ns  = (ushort_t*)alloc((size_t)n_spot * DF * 2);
  ushort_t* accum_sv = (ushort_t*)alloc((size_t)n_spot * DF * 2);
  ushort_t* accum_u  = (ushort_t*)alloc((size_t)n_user * DF * 2);
  ushort_t* accum_sn = (ushort_t*)alloc((size_t)n_spot * DF * 2);
  uint2*    es_all   = (uint2*)   alloc((size_t)etot * 8);
  unsigned* rp_all   = (unsigned*)alloc(((size_t)NT + 1) * 4);
  unsigned* cur_all  = (unsigned*)alloc((size_t)NT * 4);
  unsigned* deg_all  = (unsigned*)alloc((size_t)NT * 4);
  unsigned* bsum     = (unsigned*)alloc(4096);

  // dropout keys: fold_in(key(1), t) == threefry((0,1),(0,t))
  unsigned kv0, kv1, kr0, kr1, kn0, kn1;
  threefry2x32(0u, 1u, 0u, 0u, kv0, kv1);
  threefry2x32(0u, 1u, 0u, 1u, kr0, kr1);
  threefry2x32(0u, 1u, 0u, 2u, kn0, kn1);

  dim3 blk(256);
  const int gb_user = (n_user + 127) / 128;
  const int gb_spot = (n_spot + 127) / 128;
  const int gb_e = (etot + 255) / 256;
  const int nb_scan = (NT + SCAN_E - 1) / SCAN_E;

  // CSR build (unified)
  hipMemsetAsync(deg_all, 0, (size_t)NT * 4, stream);
  hist3<<<gb_e, blk, 0, stream>>>(visit_dst, rev_dst, near_dst, deg_all,
                                  e_visit, e_rev, e_near, segU, segN);
  scanA<<<nb_scan, blk, 0, stream>>>(deg_all, bsum, NT);
  scanB<<<1, 1024, 0, stream>>>(bsum, rp_all, nb_scan, NT);
  scanC<<<nb_scan, blk, 0, stream>>>(deg_all, bsum, rp_all, cur_all, NT);
  fill3<<<gb_e, blk, 0, stream>>>(visit_src, visit_dst, rev_src, rev_dst,
                                  near_src, near_dst, cur_all, es_all,
                                  e_visit, e_rev, e_near, segU, segN);

  // source-side projections (bf16)
  gemm_mfma<0><<<gb_user, blk, 0, stream>>>(x_user, W_visit_src, nullptr, n_user,
                                            proj_vs, nullptr, nullptr, nullptr);
  gemm_mfma<0><<<gb_spot, blk, 0, stream>>>(x_spot, W_rev_src, nullptr, n_spot,
                                            proj_rs, nullptr, nullptr, nullptr);
  gemm_mfma<0><<<gb_spot, blk, 0, stream>>>(x_spot, W_near_src, nullptr, n_spot,
                                            proj_ns, nullptr, nullptr, nullptr);

  // gather-reduce (rowptr offset by segment base; es slots are global)
  gather_reduce<<<(n_spot + 3) / 4, blk, 0, stream>>>(
      proj_vs, es_all, rp_all, accum_sv, n_spot, emax, kv0, kv1);
  gather_reduce<<<(n_user + 3) / 4, blk, 0, stream>>>(
      proj_rs, es_all, rp_all + segU, accum_u, n_user, emax, kr0, kr1);
  gather_reduce<<<(n_spot + 3) / 4, blk, 0, stream>>>(
      proj_ns, es_all, rp_all + segN, accum_sn, n_spot, emax, kn0, kn1);

  // finalize: fused tgt-projection + mean-add + relu
  gemm_mfma<1><<<gb_user, blk, 0, stream>>>(x_user, W_rev_tgt, nullptr, n_user,
                                            nullptr, out_user, accum_u, nullptr);
  gemm_mfma<2><<<gb_spot, blk, 0, stream>>>(x_spot, W_visit_tgt, W_near_tgt, n_spot,
                                            nullptr, out_spot, accum_sv, accum_sn);
}

// Round 7
// 608.691 us; speedup vs baseline: 6.9077x; 1.0135x over previous
//
#include <hip/hip_runtime.h>
#include <stdint.h>

#define DF 128
typedef unsigned short ushort_t;
typedef __attribute__((ext_vector_type(8))) short short8v;   // 8 bf16 (4 VGPRs)
typedef __attribute__((ext_vector_type(4))) float f32x4;

// ---------------- Threefry-2x32 (JAX-compatible, 20 rounds) ----------------
__host__ __device__ __forceinline__ unsigned rotl32(unsigned v, int r) {
  return __builtin_rotateleft32(v, (unsigned)r);   // fshl -> v_alignbit_b32
}

__host__ __device__ __forceinline__ void threefry2x32(
    unsigned k0, unsigned k1, unsigned c0, unsigned c1,
    unsigned& o0, unsigned& o1) {
  unsigned kx = k0 ^ k1 ^ 0x1BD11BDAu;
  unsigned x0 = c0 + k0;
  unsigned x1 = c1 + k1;
#define TF_R(r) { x0 += x1; x1 = rotl32(x1, r); x1 ^= x0; }
  TF_R(13) TF_R(15) TF_R(26) TF_R(6)
  x0 += k1; x1 += kx + 1u;
  TF_R(17) TF_R(29) TF_R(16) TF_R(24)
  x0 += kx; x1 += k0 + 2u;
  TF_R(13) TF_R(15) TF_R(26) TF_R(6)
  x0 += k0; x1 += k1 + 3u;
  TF_R(17) TF_R(29) TF_R(16) TF_R(24)
  x0 += k1; x1 += kx + 4u;
  TF_R(13) TF_R(15) TF_R(26) TF_R(6)
  x0 += kx; x1 += k0 + 5u;
#undef TF_R
  o0 = x0; o1 = x1;
}

#define KEEP_THR 0xE6666600u   // uniform(bits) < 0.9f

// ---------------- bf16 helpers (RTNE) --------------------------------------
__device__ __forceinline__ ushort_t f2bf(float f) {
  unsigned u = __float_as_uint(f);
  unsigned r = (u + 0x7fffu + ((u >> 16) & 1u)) >> 16;
  return (ushort_t)r;
}
__device__ __forceinline__ float bf2f(ushort_t h) {
  return __uint_as_float(((unsigned)h) << 16);
}
__device__ __forceinline__ unsigned umin_u(unsigned a, unsigned b) {
  return a < b ? a : b;
}

// ---------------- MFMA GEMM [M,128] x [128,128] ----------------------------
// EPI 0: outB = bf16(X@W1)
// EPI 1: outF = relu(X@W1 + mean1)            (mean1 bf16)
// EPI 2: outF = relu(0.5*(X@(W1+W2) + mean1 + mean2))
template <int EPI>
__global__ __launch_bounds__(256) void gemm_mfma(
    const float* __restrict__ X, const float* __restrict__ W1,
    const float* __restrict__ W2, int M,
    ushort_t* __restrict__ outB, float* __restrict__ outF,
    const ushort_t* __restrict__ m1, const ushort_t* __restrict__ m2) {
  __shared__ ushort_t Wt[DF][136];   // W^T bf16, padded
  const int t = threadIdx.x;
  const int lane = t & 63;
  const int w = t >> 6;
  const int lr = lane & 15;     // A-row / B-col within 16
  const int kg = lane >> 4;     // k-group 0..3
  const int rbase = blockIdx.x * 128;

#pragma unroll
  for (int i = 0; i < 16; ++i) {
    int q = t + i * 256;
    int k = q >> 5;
    int c4 = (q & 31) * 4;
    float4 wv = *reinterpret_cast<const float4*>(&W1[k * DF + c4]);
    if constexpr (EPI == 2) {
      float4 w2 = *reinterpret_cast<const float4*>(&W2[k * DF + c4]);
      wv.x += w2.x; wv.y += w2.y; wv.z += w2.z; wv.w += w2.w;
    }
    Wt[c4 + 0][k] = f2bf(wv.x);
    Wt[c4 + 1][k] = f2bf(wv.y);
    Wt[c4 + 2][k] = f2bf(wv.z);
    Wt[c4 + 3][k] = f2bf(wv.w);
  }
  __syncthreads();

  f32x4 acc[2][8];
#pragma unroll
  for (int rg = 0; rg < 2; ++rg)
#pragma unroll
    for (int n = 0; n < 8; ++n) acc[rg][n] = (f32x4){0.f, 0.f, 0.f, 0.f};

#pragma unroll
  for (int kt = 0; kt < 4; ++kt) {
    const int kb = kt * 32 + kg * 8;
    short8v a[2];
#pragma unroll
    for (int rg = 0; rg < 2; ++rg) {
      int r = rbase + w * 32 + rg * 16 + lr;
      float4 x0 = make_float4(0.f, 0.f, 0.f, 0.f);
      float4 x1 = x0;
      if (r < M) {
        x0 = *reinterpret_cast<const float4*>(&X[(size_t)r * DF + kb]);
        x1 = *reinterpret_cast<const float4*>(&X[(size_t)r * DF + kb + 4]);
      }
      short8v av;
      av[0] = (short)f2bf(x0.x); av[1] = (short)f2bf(x0.y);
      av[2] = (short)f2bf(x0.z); av[3] = (short)f2bf(x0.w);
      av[4] = (short)f2bf(x1.x); av[5] = (short)f2bf(x1.y);
      av[6] = (short)f2bf(x1.z); av[7] = (short)f2bf(x1.w);
      a[rg] = av;
    }
#pragma unroll
    for (int n = 0; n < 8; ++n) {
      short8v b = *reinterpret_cast<const short8v*>(&Wt[n * 16 + lr][kb]);
#pragma unroll
      for (int rg = 0; rg < 2; ++rg)
        acc[rg][n] = __builtin_amdgcn_mfma_f32_16x16x32_bf16(a[rg], b, acc[rg][n], 0, 0, 0);
    }
  }

#pragma unroll
  for (int rg = 0; rg < 2; ++rg) {
    const int rb = rbase + w * 32 + rg * 16 + kg * 4;
#pragma unroll
    for (int n = 0; n < 8; ++n) {
      const int col = n * 16 + lr;
#pragma unroll
      for (int j = 0; j < 4; ++j) {
        const int r = rb + j;
        if (r < M) {
          float vv = acc[rg][n][j];
          if (EPI == 0) {
            outB[(size_t)r * DF + col] = f2bf(vv);
          } else if (EPI == 1) {
            outF[(size_t)r * DF + col] =
                fmaxf(vv + bf2f(m1[(size_t)r * DF + col]), 0.f);
          } else {
            outF[(size_t)r * DF + col] =
                fmaxf(0.5f * (vv + bf2f(m1[(size_t)r * DF + col])
                                 + bf2f(m2[(size_t)r * DF + col])), 0.f);
          }
        }
      }
    }
  }
}

// ---------------- CSR build (unified: segments concatenated) ---------------
__global__ __launch_bounds__(256) void hist3(
    const int* __restrict__ vd, const int* __restrict__ rd,
    const int* __restrict__ nd, unsigned* __restrict__ deg_all,
    int Ev, int Er, int En, int segU, int segN) {
  int i = blockIdx.x * 256 + threadIdx.x;
  if (i < Ev) atomicAdd(&deg_all[vd[i]], 1u);
  else if (i < Ev + Er) atomicAdd(&deg_all[segU + rd[i - Ev]], 1u);
  else if (i < Ev + Er + En) atomicAdd(&deg_all[segN + nd[i - Ev - Er]], 1u);
}

// ---- 2-level exclusive scan over deg_all[NT] -> rp_all/cur_all -------------
#define SCAN_E 2048   // 256 threads x 8 elems

__global__ __launch_bounds__(256) void scanA(
    const unsigned* __restrict__ deg, unsigned* __restrict__ bsum, int NT) {
  __shared__ unsigned sm[256];
  const int t = threadIdx.x;
  const int base = blockIdx.x * SCAN_E + t * 8;
  unsigned s = 0;
#pragma unroll
  for (int j = 0; j < 8; ++j) {
    int i = base + j;
    s += (i < NT) ? deg[i] : 0u;
  }
  sm[t] = s;
  __syncthreads();
  for (int off = 128; off; off >>= 1) {
    if (t < off) sm[t] += sm[t + off];
    __syncthreads();
  }
  if (t == 0) bsum[blockIdx.x] = sm[0];
}

__global__ __launch_bounds__(1024) void scanB(
    unsigned* __restrict__ bsum, unsigned* __restrict__ rp_all,
    int nb, int NT) {
  __shared__ unsigned sm[1024];
  const int t = threadIdx.x;
  unsigned v = (t < nb) ? bsum[t] : 0u;
  sm[t] = v;
  __syncthreads();
  for (int off = 1; off < 1024; off <<= 1) {
    unsigned u = (t >= off) ? sm[t - off] : 0u;
    __syncthreads();
    sm[t] += u;
    __syncthreads();
  }
  if (t < nb) bsum[t] = sm[t] - v;            // exclusive
  if (t == nb - 1) rp_all[NT] = sm[t];        // grand total
}

__global__ __launch_bounds__(256) void scanC(
    const unsigned* __restrict__ deg, const unsigned* __restrict__ bsum,
    unsigned* __restrict__ rp, unsigned* __restrict__ cur, int NT) {
  __shared__ unsigned sm[256];
  const int t = threadIdx.x;
  const int base = blockIdx.x * SCAN_E + t * 8;
  unsigned vals[8];
  unsigned s = 0;
#pragma unroll
  for (int j = 0; j < 8; ++j) {
    int i = base + j;
    vals[j] = (i < NT) ? deg[i] : 0u;
    s += vals[j];
  }
  sm[t] = s;
  __syncthreads();
  for (int off = 1; off < 256; off <<= 1) {
    unsigned u = (t >= off) ? sm[t - off] : 0u;
    __syncthreads();
    sm[t] += u;
    __syncthreads();
  }
  unsigned run = bsum[blockIdx.x] + sm[t] - s;  // exclusive at this thread
#pragma unroll
  for (int j = 0; j < 8; ++j) {
    int i = base + j;
    if (i < NT) { rp[i] = run; cur[i] = run; }
    run += vals[j];
  }
}

// fill: es_all[slot] = (edge_id, src_id), slots global across segments
__global__ __launch_bounds__(256) void fill3(
    const int* __restrict__ vs, const int* __restrict__ vd,
    const int* __restrict__ rs, const int* __restrict__ rd,
    const int* __restrict__ ns, const int* __restrict__ nd,
    unsigned* __restrict__ cur_all, uint2* __restrict__ es_all,
    int Ev, int Er, int En, int segU, int segN) {
  int i = blockIdx.x * 256 + threadIdx.x;
  if (i < Ev) {
    unsigned slot = atomicAdd(&cur_all[vd[i]], 1u);
    es_all[slot] = make_uint2((unsigned)i, (unsigned)vs[i]);
  } else if (i < Ev + Er) {
    int e = i - Ev;
    unsigned slot = atomicAdd(&cur_all[segU + rd[e]], 1u);
    es_all[slot] = make_uint2((unsigned)e, (unsigned)rs[e]);
  } else if (i < Ev + Er + En) {
    int e = i - Ev - Er;
    unsigned slot = atomicAdd(&cur_all[segN + nd[e]], 1u);
    es_all[slot] = make_uint2((unsigned)e, (unsigned)ns[e]);
  }
}

// ---------------- fused gather-reduce: one wave per dst row -----------------
// Split-wave pair loop: lanes 0-31 process edge i, lanes 32-63 edge i+1;
// each lane covers 4 features (one dwordx2 gather), 4 threefry chains/iter.
// Cross-half shfl_xor(32) combine once per row. Segment (proj,key) selected
// per wave from unified row id d; accumulators contiguous in accum_all.
__global__ __launch_bounds__(256) void gather_reduce_all(
    const ushort_t* __restrict__ proj_v, const ushort_t* __restrict__ proj_r,
    const ushort_t* __restrict__ proj_n, const uint2* __restrict__ es,
    const unsigned* __restrict__ rp, ushort_t* __restrict__ accum_all,
    int NT, int segU, int segN, unsigned emax,
    unsigned kv0, unsigned kv1, unsigned kr0, unsigned kr1,
    unsigned kn0, unsigned kn1) {
  const int lane = threadIdx.x & 63;
  int d = blockIdx.x * 4 + (threadIdx.x >> 6);
  d = __builtin_amdgcn_readfirstlane(d);
  if (d >= NT) return;

  const ushort_t* proj;
  unsigned k0, k1;
  if (d < segU)      { proj = proj_v; k0 = kv0; k1 = kv1; }
  else if (d < segN) { proj = proj_r; k0 = kr0; k1 = kr1; }
  else               { proj = proj_n; k0 = kn0; k1 = kn1; }

  const unsigned b0 = __builtin_amdgcn_readfirstlane(rp[d]);
  const unsigned n  = __builtin_amdgcn_readfirstlane(rp[d + 1]) - b0;

  const bool hi = lane >= 32;
  const unsigned l31 = (unsigned)(lane & 31);
  const unsigned voff8 = l31 * 8u;          // byte offset of this lane's dwordx2

  const unsigned npairs = n >> 1;
  const unsigned odd = n & 1u;

  // pair-id pipeline (scalar)
  uint2 P0 = es[umin_u(b0, emax)];
  uint2 P1 = es[umin_u(b0 + 1u, emax)];
  unsigned eA = __builtin_amdgcn_readfirstlane(P0.x);
  unsigned sA = __builtin_amdgcn_readfirstlane(P0.y);
  unsigned eB = __builtin_amdgcn_readfirstlane(P1.x);
  unsigned sB = __builtin_amdgcn_readfirstlane(P1.y);

  float a0 = 0.f, a1 = 0.f, a2 = 0.f, a3 = 0.f;

  for (unsigned p = 0; p < npairs; ++p) {
    const unsigned src = hi ? sB : sA;
    const unsigned eid = hi ? eB : eA;
    // gather 4 features (8 bytes) of this half's edge
    const uint2 g = *reinterpret_cast<const uint2*>(
        reinterpret_cast<const char*>(proj) + ((size_t)src << 8) + voff8);
    // prefetch next pair's ids (scalar)
    uint2 Pn0 = es[umin_u(b0 + 2u * p + 2u, emax)];
    uint2 Pn1 = es[umin_u(b0 + 2u * p + 3u, emax)];

    const unsigned cb = eid * 128u + l31 * 4u;
    unsigned r0a, r0b, r1a, r1b, r2a, r2b, r3a, r3b;
    threefry2x32(k0, k1, 0u, cb + 0u, r0a, r0b);
    threefry2x32(k0, k1, 0u, cb + 1u, r1a, r1b);
    threefry2x32(k0, k1, 0u, cb + 2u, r2a, r2b);
    threefry2x32(k0, k1, 0u, cb + 3u, r3a, r3b);
    const float m0 = ((r0a ^ r0b) < KEEP_THR) ? (1.0f / 0.9f) : 0.f;
    const float m1 = ((r1a ^ r1b) < KEEP_THR) ? (1.0f / 0.9f) : 0.f;
    const float m2 = ((r2a ^ r2b) < KEEP_THR) ? (1.0f / 0.9f) : 0.f;
    const float m3 = ((r3a ^ r3b) < KEEP_THR) ? (1.0f / 0.9f) : 0.f;
    a0 = fmaf(__uint_as_float(g.x << 16), m0, a0);
    a1 = fmaf(__uint_as_float(g.x & 0xffff0000u), m1, a1);
    a2 = fmaf(__uint_as_float(g.y << 16), m2, a2);
    a3 = fmaf(__uint_as_float(g.y & 0xffff0000u), m3, a3);

    eA = __builtin_amdgcn_readfirstlane(Pn0.x);
    sA = __builtin_amdgcn_readfirstlane(Pn0.y);
    eB = __builtin_amdgcn_readfirstlane(Pn1.x);
    sB = __builtin_amdgcn_readfirstlane(Pn1.y);
  }

  if (odd) {
    // last edge: both halves gather row sA, upper half contributes 0
    const uint2 g = *reinterpret_cast<const uint2*>(
        reinterpret_cast<const char*>(proj) + ((size_t)sA << 8) + voff8);
    const unsigned cb = eA * 128u + l31 * 4u;
    unsigned r0a, r0b, r1a, r1b, r2a, r2b, r3a, r3b;
    threefry2x32(k0, k1, 0u, cb + 0u, r0a, r0b);
    threefry2x32(k0, k1, 0u, cb + 1u, r1a, r1b);
    threefry2x32(k0, k1, 0u, cb + 2u, r2a, r2b);
    threefry2x32(k0, k1, 0u, cb + 3u, r3a, r3b);
    const float sc = hi ? 0.f : (1.0f / 0.9f);
    const float m0 = ((r0a ^ r0b) < KEEP_THR) ? sc : 0.f;
    const float m1 = ((r1a ^ r1b) < KEEP_THR) ? sc : 0.f;
    const float m2 = ((r2a ^ r2b) < KEEP_THR) ? sc : 0.f;
    const float m3 = ((r3a ^ r3b) < KEEP_THR) ? sc : 0.f;
    a0 = fmaf(__uint_as_float(g.x << 16), m0, a0);
    a1 = fmaf(__uint_as_float(g.x & 0xffff0000u), m1, a1);
    a2 = fmaf(__uint_as_float(g.y << 16), m2, a2);
    a3 = fmaf(__uint_as_float(g.y & 0xffff0000u), m3, a3);
  }

  // cross-half combine: lane l and l+32 hold partial sums of the same feats
  a0 += __shfl_xor(a0, 32);
  a1 += __shfl_xor(a1, 32);
  a2 += __shfl_xor(a2, 32);
  a3 += __shfl_xor(a3, 32);

  const float inv = 1.0f / fmaxf((float)n, 1.0f);
  // lane<32 writes dword 2*l31 (feats 4l,4l+1); lane>=32 writes 2*l31+1
  const float u0 = hi ? a2 : a0;
  const float u1 = hi ? a3 : a1;
  const unsigned pk =
      ((unsigned)f2bf(u0 * inv)) | (((unsigned)f2bf(u1 * inv)) << 16);
  unsigned* out = reinterpret_cast<unsigned*>(accum_all) + (size_t)d * 64;
  out[2u * l31 + (hi ? 1u : 0u)] = pk;
}

// ---------------------------------------------------------------------------
extern "C" void kernel_launch(void* const* d_in, const int* in_sizes, int n_in,
                              void* d_out, int out_size, void* d_ws, size_t ws_size,
                              hipStream_t stream) {
  const float* x_user      = (const float*)d_in[0];
  const float* x_spot      = (const float*)d_in[1];
  const float* W_visit_src = (const float*)d_in[2];
  const float* W_visit_tgt = (const float*)d_in[3];
  const float* W_rev_src   = (const float*)d_in[4];
  const float* W_rev_tgt   = (const float*)d_in[5];
  const float* W_near_src  = (const float*)d_in[6];
  const float* W_near_tgt  = (const float*)d_in[7];
  const int* visit_src = (const int*)d_in[8];
  const int* visit_dst = (const int*)d_in[9];
  const int* rev_src   = (const int*)d_in[10];
  const int* rev_dst   = (const int*)d_in[11];
  const int* near_src  = (const int*)d_in[12];
  const int* near_dst  = (const int*)d_in[13];

  const int n_user = in_sizes[0] / DF;
  const int n_spot = in_sizes[1] / DF;
  const int e_visit = in_sizes[8];
  const int e_rev   = in_sizes[10];
  const int e_near  = in_sizes[12];

  float* out_user = (float*)d_out;
  float* out_spot = out_user + (size_t)n_user * DF;

  const int NT = n_spot + n_user + n_spot;       // unified row count
  const int segU = n_spot;
  const int segN = n_spot + n_user;
  const int etot = e_visit + e_rev + e_near;
  const unsigned emax = (unsigned)(etot - 1);

  // ---- workspace ----
  char* ws = (char*)d_ws;
  size_t off = 0;
  auto alloc = [&](size_t bytes) -> void* {
    void* p = ws + off;
    off += (bytes + 255) & ~(size_t)255;
    return p;
  };
  ushort_t* proj_vs   = (ushort_t*)alloc((size_t)n_user * DF * 2);
  ushort_t* proj_rs   = (ushort_t*)alloc((size_t)n_spot * DF * 2);
  ushort_t* proj_ns   = (ushort_t*)alloc((size_t)n_spot * DF * 2);
  ushort_t* accum_all = (ushort_t*)alloc((size_t)NT * DF * 2);
  uint2*    es_all    = (uint2*)   alloc((size_t)etot * 8);
  unsigned* rp_all    = (unsigned*)alloc(((size_t)NT + 1) * 4);
  unsigned* cur_all   = (unsigned*)alloc((size_t)NT * 4);
  unsigned* deg_all   = (unsigned*)alloc((size_t)NT * 4);
  unsigned* bsum      = (unsigned*)alloc(4096);

  // mean rows per segment (contiguous in accum_all)
  ushort_t* mean_sv = accum_all;                         // rows [0, n_spot)
  ushort_t* mean_u  = accum_all + (size_t)segU * DF;     // rows [segU, segN)
  ushort_t* mean_sn = accum_all + (size_t)segN * DF;     // rows [segN, NT)

  // dropout keys: fold_in(key(1), t) == threefry((0,1),(0,t))
  unsigned kv0, kv1, kr0, kr1, kn0, kn1;
  threefry2x32(0u, 1u, 0u, 0u, kv0, kv1);
  threefry2x32(0u, 1u, 0u, 1u, kr0, kr1);
  threefry2x32(0u, 1u, 0u, 2u, kn0, kn1);

  dim3 blk(256);
  const int gb_user = (n_user + 127) / 128;
  const int gb_spot = (n_spot + 127) / 128;
  const int gb_e = (etot + 255) / 256;
  const int nb_scan = (NT + SCAN_E - 1) / SCAN_E;

  // CSR build (unified)
  hipMemsetAsync(deg_all, 0, (size_t)NT * 4, stream);
  hist3<<<gb_e, blk, 0, stream>>>(visit_dst, rev_dst, near_dst, deg_all,
                                  e_visit, e_rev, e_near, segU, segN);
  scanA<<<nb_scan, blk, 0, stream>>>(deg_all, bsum, NT);
  scanB<<<1, 1024, 0, stream>>>(bsum, rp_all, nb_scan, NT);
  scanC<<<nb_scan, blk, 0, stream>>>(deg_all, bsum, rp_all, cur_all, NT);
  fill3<<<gb_e, blk, 0, stream>>>(visit_src, visit_dst, rev_src, rev_dst,
                                  near_src, near_dst, cur_all, es_all,
                                  e_visit, e_rev, e_near, segU, segN);

  // source-side projections (bf16)
  gemm_mfma<0><<<gb_user, blk, 0, stream>>>(x_user, W_visit_src, nullptr, n_user,
                                            proj_vs, nullptr, nullptr, nullptr);
  gemm_mfma<0><<<gb_spot, blk, 0, stream>>>(x_spot, W_rev_src, nullptr, n_spot,
                                            proj_rs, nullptr, nullptr, nullptr);
  gemm_mfma<0><<<gb_spot, blk, 0, stream>>>(x_spot, W_near_src, nullptr, n_spot,
                                            proj_ns, nullptr, nullptr, nullptr);

  // fused gather-reduce over all NT rows (one dispatch)
  gather_reduce_all<<<(NT + 3) / 4, blk, 0, stream>>>(
      proj_vs, proj_rs, proj_ns, es_all, rp_all, accum_all,
      NT, segU, segN, emax, kv0, kv1, kr0, kr1, kn0, kn1);

  // finalize: fused tgt-projection + mean-add + relu
  gemm_mfma<1><<<gb_user, blk, 0, stream>>>(x_user, W_rev_tgt, nullptr, n_user,
                                            nullptr, out_user, mean_u, nullptr);
  gemm_mfma<2><<<gb_spot, blk, 0, stream>>>(x_spot, W_visit_tgt, W_near_tgt, n_spot,
                                            nullptr, out_spot, mean_sv, mean_sn);
}

// Round 8
// 559.906 us; speedup vs baseline: 7.5096x; 1.0871x over previous
//
#include <hip/hip_runtime.h>
#include <stdint.h>

#define DF 128
typedef unsigned short ushort_t;
typedef __attribute__((ext_vector_type(8))) short short8v;   // 8 bf16 (4 VGPRs)
typedef __attribute__((ext_vector_type(4))) float f32x4;

// ---------------- Threefry-2x32 (JAX-compatible, 20 rounds) ----------------
__host__ __device__ __forceinline__ unsigned rotl32(unsigned v, int r) {
  return __builtin_rotateleft32(v, (unsigned)r);   // fshl -> v_alignbit_b32
}

__host__ __device__ __forceinline__ void threefry2x32(
    unsigned k0, unsigned k1, unsigned c0, unsigned c1,
    unsigned& o0, unsigned& o1) {
  unsigned kx = k0 ^ k1 ^ 0x1BD11BDAu;
  unsigned x0 = c0 + k0;
  unsigned x1 = c1 + k1;
#define TF_R(r) { x0 += x1; x1 = rotl32(x1, r); x1 ^= x0; }
  TF_R(13) TF_R(15) TF_R(26) TF_R(6)
  x0 += k1; x1 += kx + 1u;
  TF_R(17) TF_R(29) TF_R(16) TF_R(24)
  x0 += kx; x1 += k0 + 2u;
  TF_R(13) TF_R(15) TF_R(26) TF_R(6)
  x0 += k0; x1 += k1 + 3u;
  TF_R(17) TF_R(29) TF_R(16) TF_R(24)
  x0 += k1; x1 += kx + 4u;
  TF_R(13) TF_R(15) TF_R(26) TF_R(6)
  x0 += kx; x1 += k0 + 5u;
#undef TF_R
  o0 = x0; o1 = x1;
}

#define KEEP_THR 0xE6666600u   // uniform(bits) < 0.9f

// ---------------- bf16 helpers (RTNE) --------------------------------------
__device__ __forceinline__ ushort_t f2bf(float f) {
  unsigned u = __float_as_uint(f);
  unsigned r = (u + 0x7fffu + ((u >> 16) & 1u)) >> 16;
  return (ushort_t)r;
}
__device__ __forceinline__ float bf2f(unsigned h) {
  return __uint_as_float(h << 16);
}
__device__ __forceinline__ unsigned umin_u(unsigned a, unsigned b) {
  return a < b ? a : b;
}

// =================== GEMM core (shared by both kernels) =====================
// MFMA 16x16x32 bf16; C/D: col=lane&15, row=(lane>>4)*4+j.
// Wt staged transposed at ushort stride 136 (conflict-free b128 reads).
// acc[rg][n] covers rows w*32+rg*16+kg*4.. and cols n*16+lr.
#define WT(k, c) sm_u[(k) * 136 + (c)]
#define CTB(r, c) sm_u[(r) * 144 + (c)]       // bf16 repack (EPI0), 36864 B
#define CTF(r, c) sm_f[(r) * 68 + (c)]        // f32 repack (col-half), 34816 B

__device__ __forceinline__ void gemm_core(
    const float* __restrict__ X, const float* __restrict__ W1,
    const float* __restrict__ W2, bool sumW, int M, int rbase,
    ushort_t* sm_u, f32x4 acc[2][8]) {
  const int t = threadIdx.x;
  const int lane = t & 63;
  const int w = t >> 6;
  const int lr = lane & 15;
  const int kg = lane >> 4;

  // stage W (optionally W1+W2) transposed as bf16
#pragma unroll
  for (int i = 0; i < 16; ++i) {
    int q = t + i * 256;
    int k = q >> 5;
    int c4 = (q & 31) * 4;
    float4 wv = *reinterpret_cast<const float4*>(&W1[k * DF + c4]);
    if (sumW) {
      float4 w2 = *reinterpret_cast<const float4*>(&W2[k * DF + c4]);
      wv.x += w2.x; wv.y += w2.y; wv.z += w2.z; wv.w += w2.w;
    }
    WT(c4 + 0, k) = f2bf(wv.x);
    WT(c4 + 1, k) = f2bf(wv.y);
    WT(c4 + 2, k) = f2bf(wv.z);
    WT(c4 + 3, k) = f2bf(wv.w);
  }
  __syncthreads();

#pragma unroll
  for (int rg = 0; rg < 2; ++rg)
#pragma unroll
    for (int n = 0; n < 8; ++n) acc[rg][n] = (f32x4){0.f, 0.f, 0.f, 0.f};

#pragma unroll
  for (int kt = 0; kt < 4; ++kt) {
    const int kb = kt * 32 + kg * 8;
    short8v a[2];
#pragma unroll
    for (int rg = 0; rg < 2; ++rg) {
      int r = rbase + w * 32 + rg * 16 + lr;
      float4 x0 = make_float4(0.f, 0.f, 0.f, 0.f);
      float4 x1 = x0;
      if (r < M) {
        x0 = *reinterpret_cast<const float4*>(&X[(size_t)r * DF + kb]);
        x1 = *reinterpret_cast<const float4*>(&X[(size_t)r * DF + kb + 4]);
      }
      short8v av;
      av[0] = (short)f2bf(x0.x); av[1] = (short)f2bf(x0.y);
      av[2] = (short)f2bf(x0.z); av[3] = (short)f2bf(x0.w);
      av[4] = (short)f2bf(x1.x); av[5] = (short)f2bf(x1.y);
      av[6] = (short)f2bf(x1.z); av[7] = (short)f2bf(x1.w);
      a[rg] = av;
    }
#pragma unroll
    for (int n = 0; n < 8; ++n) {
      short8v b = *reinterpret_cast<const short8v*>(&WT(n * 16 + lr, kb));
#pragma unroll
      for (int rg = 0; rg < 2; ++rg)
        acc[rg][n] = __builtin_amdgcn_mfma_f32_16x16x32_bf16(a[rg], b, acc[rg][n], 0, 0, 0);
    }
  }
}

// ---------------- fused source-projection GEMM (3 outputs, EPI0) ------------
__global__ __launch_bounds__(256) void proj3_gemm(
    const float* __restrict__ x_user, const float* __restrict__ x_spot,
    const float* __restrict__ Wv, const float* __restrict__ Wr,
    const float* __restrict__ Wn, int n_user, int n_spot,
    ushort_t* __restrict__ pv, ushort_t* __restrict__ pr,
    ushort_t* __restrict__ pn, int gbU, int gbS) {
  __shared__ __align__(16) ushort_t sm_u[18432];   // 36864 B
  const int b = blockIdx.x;
  const float* X; const float* W; ushort_t* out; int M; int rbase;
  if (b < gbU)            { X = x_user; W = Wv; out = pv; M = n_user; rbase = b * 128; }
  else if (b < gbU + gbS) { X = x_spot; W = Wr; out = pr; M = n_spot; rbase = (b - gbU) * 128; }
  else                    { X = x_spot; W = Wn; out = pn; M = n_spot; rbase = (b - gbU - gbS) * 128; }

  f32x4 acc[2][8];
  gemm_core(X, W, nullptr, false, M, rbase, sm_u, acc);

  const int t = threadIdx.x;
  const int lane = t & 63;
  const int w = t >> 6;
  const int lr = lane & 15;
  const int kg = lane >> 4;

  __syncthreads();   // Wt reads done before overwrite
#pragma unroll
  for (int rg = 0; rg < 2; ++rg) {
    const int rowb = w * 32 + rg * 16 + kg * 4;
#pragma unroll
    for (int n = 0; n < 8; ++n) {
      const int col = n * 16 + lr;
#pragma unroll
      for (int j = 0; j < 4; ++j) CTB(rowb + j, col) = f2bf(acc[rg][n][j]);
    }
  }
  __syncthreads();
#pragma unroll
  for (int i = 0; i < 8; ++i) {
    const int u = t + i * 256;
    const int row = u >> 4, ch = u & 15;
    const int grow = rbase + row;
    if (grow < M)
      *reinterpret_cast<uint4*>(&out[(size_t)grow * DF + ch * 8]) =
          *reinterpret_cast<const uint4*>(&CTB(row, ch * 8));
  }
}

// ---------------- fused finalize GEMM (EPI1 user / EPI2 spot) ---------------
__global__ __launch_bounds__(256) void final2_gemm(
    const float* __restrict__ x_user, const float* __restrict__ x_spot,
    const float* __restrict__ Wrt, const float* __restrict__ Wvt,
    const float* __restrict__ Wnt, int n_user, int n_spot,
    float* __restrict__ out_user, float* __restrict__ out_spot,
    const ushort_t* __restrict__ mean_u, const ushort_t* __restrict__ mean_sv,
    const ushort_t* __restrict__ mean_sn, int gbU) {
  __shared__ __align__(16) ushort_t sm_u[17408];   // 34816 B (Wt / CTF alias)
  float* sm_f_raw = reinterpret_cast<float*>(sm_u);
#define sm_f sm_f_raw
  const int b = blockIdx.x;
  const bool epi2 = (b >= gbU);
  const float* X; const float* W1; const float* W2; float* outF;
  const ushort_t* m1; const ushort_t* m2; int M; int rbase;
  if (!epi2) {
    X = x_user; W1 = Wrt; W2 = nullptr; outF = out_user;
    m1 = mean_u; m2 = nullptr; M = n_user; rbase = b * 128;
  } else {
    X = x_spot; W1 = Wvt; W2 = Wnt; outF = out_spot;
    m1 = mean_sv; m2 = mean_sn; M = n_spot; rbase = (b - gbU) * 128;
  }

  f32x4 acc[2][8];
  gemm_core(X, W1, W2, epi2, M, rbase, sm_u, acc);

  const int t = threadIdx.x;
  const int lane = t & 63;
  const int w = t >> 6;
  const int lr = lane & 15;
  const int kg = lane >> 4;

  // two column-half passes through f32 LDS, coalesced mean-add + relu + store
#pragma unroll
  for (int h = 0; h < 2; ++h) {
    __syncthreads();   // prior reads (Wt or pass-0) done
#pragma unroll
    for (int rg = 0; rg < 2; ++rg) {
      const int rowb = w * 32 + rg * 16 + kg * 4;
#pragma unroll
      for (int n2 = 0; n2 < 4; ++n2) {
        const int n = h * 4 + n2;
        const int col = n2 * 16 + lr;
#pragma unroll
        for (int j = 0; j < 4; ++j) CTF(rowb + j, col) = acc[rg][n][j];
      }
    }
    __syncthreads();
#pragma unroll
    for (int i = 0; i < 8; ++i) {
      const int u = t + i * 256;
      const int row = u >> 4;
      const int c4 = (u & 15) * 4;
      const int grow = rbase + row;
      if (grow < M) {
        const float4 vv = *reinterpret_cast<const float4*>(&CTF(row, c4));
        const int col = h * 64 + c4;
        const uint2 mb = *reinterpret_cast<const uint2*>(&m1[(size_t)grow * DF + col]);
        float a0 = bf2f(mb.x & 0xffffu), a1 = bf2f(mb.x >> 16);
        float a2 = bf2f(mb.y & 0xffffu), a3 = bf2f(mb.y >> 16);
        float4 r;
        if (!epi2) {
          r.x = fmaxf(vv.x + a0, 0.f);
          r.y = fmaxf(vv.y + a1, 0.f);
          r.z = fmaxf(vv.z + a2, 0.f);
          r.w = fmaxf(vv.w + a3, 0.f);
        } else {
          const uint2 nb = *reinterpret_cast<const uint2*>(&m2[(size_t)grow * DF + col]);
          r.x = fmaxf(0.5f * (vv.x + a0 + bf2f(nb.x & 0xffffu)), 0.f);
          r.y = fmaxf(0.5f * (vv.y + a1 + bf2f(nb.x >> 16)), 0.f);
          r.z = fmaxf(0.5f * (vv.z + a2 + bf2f(nb.y & 0xffffu)), 0.f);
          r.w = fmaxf(0.5f * (vv.w + a3 + bf2f(nb.y >> 16)), 0.f);
        }
        *reinterpret_cast<float4*>(&outF[(size_t)grow * DF + col]) = r;
      }
    }
  }
#undef sm_f
}

// ---------------- CSR build (unified: segments concatenated) ---------------
__global__ __launch_bounds__(256) void hist3(
    const int* __restrict__ vd, const int* __restrict__ rd,
    const int* __restrict__ nd, unsigned* __restrict__ deg_all,
    int Ev, int Er, int En, int segU, int segN) {
  int i = blockIdx.x * 256 + threadIdx.x;
  if (i < Ev) atomicAdd(&deg_all[vd[i]], 1u);
  else if (i < Ev + Er) atomicAdd(&deg_all[segU + rd[i - Ev]], 1u);
  else if (i < Ev + Er + En) atomicAdd(&deg_all[segN + nd[i - Ev - Er]], 1u);
}

#define SCAN_E 2048   // 256 threads x 8 elems

__global__ __launch_bounds__(256) void scanA(
    const unsigned* __restrict__ deg, unsigned* __restrict__ bsum, int NT) {
  __shared__ unsigned sm[256];
  const int t = threadIdx.x;
  const int base = blockIdx.x * SCAN_E + t * 8;
  unsigned s = 0;
#pragma unroll
  for (int j = 0; j < 8; ++j) {
    int i = base + j;
    s += (i < NT) ? deg[i] : 0u;
  }
  sm[t] = s;
  __syncthreads();
  for (int off = 128; off; off >>= 1) {
    if (t < off) sm[t] += sm[t + off];
    __syncthreads();
  }
  if (t == 0) bsum[blockIdx.x] = sm[0];
}

__global__ __launch_bounds__(1024) void scanB(
    unsigned* __restrict__ bsum, unsigned* __restrict__ rp_all,
    int nb, int NT) {
  __shared__ unsigned sm[1024];
  const int t = threadIdx.x;
  unsigned v = (t < nb) ? bsum[t] : 0u;
  sm[t] = v;
  __syncthreads();
  for (int off = 1; off < 1024; off <<= 1) {
    unsigned u = (t >= off) ? sm[t - off] : 0u;
    __syncthreads();
    sm[t] += u;
    __syncthreads();
  }
  if (t < nb) bsum[t] = sm[t] - v;            // exclusive
  if (t == nb - 1) rp_all[NT] = sm[t];        // grand total
}

__global__ __launch_bounds__(256) void scanC(
    const unsigned* __restrict__ deg, const unsigned* __restrict__ bsum,
    unsigned* __restrict__ rp, unsigned* __restrict__ cur, int NT) {
  __shared__ unsigned sm[256];
  const int t = threadIdx.x;
  const int base = blockIdx.x * SCAN_E + t * 8;
  unsigned vals[8];
  unsigned s = 0;
#pragma unroll
  for (int j = 0; j < 8; ++j) {
    int i = base + j;
    vals[j] = (i < NT) ? deg[i] : 0u;
    s += vals[j];
  }
  sm[t] = s;
  __syncthreads();
  for (int off = 1; off < 256; off <<= 1) {
    unsigned u = (t >= off) ? sm[t - off] : 0u;
    __syncthreads();
    sm[t] += u;
    __syncthreads();
  }
  unsigned run = bsum[blockIdx.x] + sm[t] - s;
#pragma unroll
  for (int j = 0; j < 8; ++j) {
    int i = base + j;
    if (i < NT) { rp[i] = run; cur[i] = run; }
    run += vals[j];
  }
}

__global__ __launch_bounds__(256) void fill3(
    const int* __restrict__ vs, const int* __restrict__ vd,
    const int* __restrict__ rs, const int* __restrict__ rd,
    const int* __restrict__ ns, const int* __restrict__ nd,
    unsigned* __restrict__ cur_all, uint2* __restrict__ es_all,
    int Ev, int Er, int En, int segU, int segN) {
  int i = blockIdx.x * 256 + threadIdx.x;
  if (i < Ev) {
    unsigned slot = atomicAdd(&cur_all[vd[i]], 1u);
    es_all[slot] = make_uint2((unsigned)i, (unsigned)vs[i]);
  } else if (i < Ev + Er) {
    int e = i - Ev;
    unsigned slot = atomicAdd(&cur_all[segU + rd[e]], 1u);
    es_all[slot] = make_uint2((unsigned)e, (unsigned)rs[e]);
  } else if (i < Ev + Er + En) {
    int e = i - Ev - Er;
    unsigned slot = atomicAdd(&cur_all[segN + nd[e]], 1u);
    es_all[slot] = make_uint2((unsigned)e, (unsigned)ns[e]);
  }
}

// ---------------- fused gather-reduce: one wave per dst row -----------------
__global__ __launch_bounds__(256) void gather_reduce_all(
    const ushort_t* __restrict__ proj_v, const ushort_t* __restrict__ proj_r,
    const ushort_t* __restrict__ proj_n, const uint2* __restrict__ es,
    const unsigned* __restrict__ rp, ushort_t* __restrict__ accum_all,
    int NT, int segU, int segN, unsigned emax,
    unsigned kv0, unsigned kv1, unsigned kr0, unsigned kr1,
    unsigned kn0, unsigned kn1) {
  const int lane = threadIdx.x & 63;
  int d = blockIdx.x * 4 + (threadIdx.x >> 6);
  d = __builtin_amdgcn_readfirstlane(d);
  if (d >= NT) return;

  const ushort_t* proj;
  unsigned k0, k1;
  if (d < segU)      { proj = proj_v; k0 = kv0; k1 = kv1; }
  else if (d < segN) { proj = proj_r; k0 = kr0; k1 = kr1; }
  else               { proj = proj_n; k0 = kn0; k1 = kn1; }

  const unsigned b0 = __builtin_amdgcn_readfirstlane(rp[d]);
  const unsigned n  = __builtin_amdgcn_readfirstlane(rp[d + 1]) - b0;

  const bool hi = lane >= 32;
  const unsigned l31 = (unsigned)(lane & 31);
  const unsigned voff8 = l31 * 8u;

  const unsigned npairs = n >> 1;
  const unsigned odd = n & 1u;

  uint2 P0 = es[umin_u(b0, emax)];
  uint2 P1 = es[umin_u(b0 + 1u, emax)];
  unsigned eA = __builtin_amdgcn_readfirstlane(P0.x);
  unsigned sA = __builtin_amdgcn_readfirstlane(P0.y);
  unsigned eB = __builtin_amdgcn_readfirstlane(P1.x);
  unsigned sB = __builtin_amdgcn_readfirstlane(P1.y);

  float a0 = 0.f, a1 = 0.f, a2 = 0.f, a3 = 0.f;

  for (unsigned p = 0; p < npairs; ++p) {
    const unsigned src = hi ? sB : sA;
    const unsigned eid = hi ? eB : eA;
    const uint2 g = *reinterpret_cast<const uint2*>(
        reinterpret_cast<const char*>(proj) + ((size_t)src << 8) + voff8);
    uint2 Pn0 = es[umin_u(b0 + 2u * p + 2u, emax)];
    uint2 Pn1 = es[umin_u(b0 + 2u * p + 3u, emax)];

    const unsigned cb = eid * 128u + l31 * 4u;
    unsigned r0a, r0b, r1a, r1b, r2a, r2b, r3a, r3b;
    threefry2x32(k0, k1, 0u, cb + 0u, r0a, r0b);
    threefry2x32(k0, k1, 0u, cb + 1u, r1a, r1b);
    threefry2x32(k0, k1, 0u, cb + 2u, r2a, r2b);
    threefry2x32(k0, k1, 0u, cb + 3u, r3a, r3b);
    const float m0 = ((r0a ^ r0b) < KEEP_THR) ? (1.0f / 0.9f) : 0.f;
    const float m1 = ((r1a ^ r1b) < KEEP_THR) ? (1.0f / 0.9f) : 0.f;
    const float m2 = ((r2a ^ r2b) < KEEP_THR) ? (1.0f / 0.9f) : 0.f;
    const float m3 = ((r3a ^ r3b) < KEEP_THR) ? (1.0f / 0.9f) : 0.f;
    a0 = fmaf(__uint_as_float(g.x << 16), m0, a0);
    a1 = fmaf(__uint_as_float(g.x & 0xffff0000u), m1, a1);
    a2 = fmaf(__uint_as_float(g.y << 16), m2, a2);
    a3 = fmaf(__uint_as_float(g.y & 0xffff0000u), m3, a3);

    eA = __builtin_amdgcn_readfirstlane(Pn0.x);
    sA = __builtin_amdgcn_readfirstlane(Pn0.y);
    eB = __builtin_amdgcn_readfirstlane(Pn1.x);
    sB = __builtin_amdgcn_readfirstlane(Pn1.y);
  }

  if (odd) {
    const uint2 g = *reinterpret_cast<const uint2*>(
        reinterpret_cast<const char*>(proj) + ((size_t)sA << 8) + voff8);
    const unsigned cb = eA * 128u + l31 * 4u;
    unsigned r0a, r0b, r1a, r1b, r2a, r2b, r3a, r3b;
    threefry2x32(k0, k1, 0u, cb + 0u, r0a, r0b);
    threefry2x32(k0, k1, 0u, cb + 1u, r1a, r1b);
    threefry2x32(k0, k1, 0u, cb + 2u, r2a, r2b);
    threefry2x32(k0, k1, 0u, cb + 3u, r3a, r3b);
    const float sc = hi ? 0.f : (1.0f / 0.9f);
    const float m0 = ((r0a ^ r0b) < KEEP_THR) ? sc : 0.f;
    const float m1 = ((r1a ^ r1b) < KEEP_THR) ? sc : 0.f;
    const float m2 = ((r2a ^ r2b) < KEEP_THR) ? sc : 0.f;
    const float m3 = ((r3a ^ r3b) < KEEP_THR) ? sc : 0.f;
    a0 = fmaf(__uint_as_float(g.x << 16), m0, a0);
    a1 = fmaf(__uint_as_float(g.x & 0xffff0000u), m1, a1);
    a2 = fmaf(__uint_as_float(g.y << 16), m2, a2);
    a3 = fmaf(__uint_as_float(g.y & 0xffff0000u), m3, a3);
  }

  a0 += __shfl_xor(a0, 32);
  a1 += __shfl_xor(a1, 32);
  a2 += __shfl_xor(a2, 32);
  a3 += __shfl_xor(a3, 32);

  const float inv = 1.0f / fmaxf((float)n, 1.0f);
  const float u0 = hi ? a2 : a0;
  const float u1 = hi ? a3 : a1;
  const unsigned pk =
      ((unsigned)f2bf(u0 * inv)) | (((unsigned)f2bf(u1 * inv)) << 16);
  unsigned* out = reinterpret_cast<unsigned*>(accum_all) + (size_t)d * 64;
  out[2u * l31 + (hi ? 1u : 0u)] = pk;
}

// ---------------------------------------------------------------------------
extern "C" void kernel_launch(void* const* d_in, const int* in_sizes, int n_in,
                              void* d_out, int out_size, void* d_ws, size_t ws_size,
                              hipStream_t stream) {
  const float* x_user      = (const float*)d_in[0];
  const float* x_spot      = (const float*)d_in[1];
  const float* W_visit_src = (const float*)d_in[2];
  const float* W_visit_tgt = (const float*)d_in[3];
  const float* W_rev_src   = (const float*)d_in[4];
  const float* W_rev_tgt   = (const float*)d_in[5];
  const float* W_near_src  = (const float*)d_in[6];
  const float* W_near_tgt  = (const float*)d_in[7];
  const int* visit_src = (const int*)d_in[8];
  const int* visit_dst = (const int*)d_in[9];
  const int* rev_src   = (const int*)d_in[10];
  const int* rev_dst   = (const int*)d_in[11];
  const int* near_src  = (const int*)d_in[12];
  const int* near_dst  = (const int*)d_in[13];

  const int n_user = in_sizes[0] / DF;
  const int n_spot = in_sizes[1] / DF;
  const int e_visit = in_sizes[8];
  const int e_rev   = in_sizes[10];
  const int e_near  = in_sizes[12];

  float* out_user = (float*)d_out;
  float* out_spot = out_user + (size_t)n_user * DF;

  const int NT = n_spot + n_user + n_spot;
  const int segU = n_spot;
  const int segN = n_spot + n_user;
  const int etot = e_visit + e_rev + e_near;
  const unsigned emax = (unsigned)(etot - 1);

  // ---- workspace ----
  char* ws = (char*)d_ws;
  size_t off = 0;
  auto alloc = [&](size_t bytes) -> void* {
    void* p = ws + off;
    off += (bytes + 255) & ~(size_t)255;
    return p;
  };
  ushort_t* proj_vs   = (ushort_t*)alloc((size_t)n_user * DF * 2);
  ushort_t* proj_rs   = (ushort_t*)alloc((size_t)n_spot * DF * 2);
  ushort_t* proj_ns   = (ushort_t*)alloc((size_t)n_spot * DF * 2);
  ushort_t* accum_all = (ushort_t*)alloc((size_t)NT * DF * 2);
  uint2*    es_all    = (uint2*)   alloc((size_t)etot * 8);
  unsigned* rp_all    = (unsigned*)alloc(((size_t)NT + 1) * 4);
  unsigned* cur_all   = (unsigned*)alloc((size_t)NT * 4);
  unsigned* deg_all   = (unsigned*)alloc((size_t)NT * 4);
  unsigned* bsum      = (unsigned*)alloc(4096);

  ushort_t* mean_sv = accum_all;
  ushort_t* mean_u  = accum_all + (size_t)segU * DF;
  ushort_t* mean_sn = accum_all + (size_t)segN * DF;

  unsigned kv0, kv1, kr0, kr1, kn0, kn1;
  threefry2x32(0u, 1u, 0u, 0u, kv0, kv1);
  threefry2x32(0u, 1u, 0u, 1u, kr0, kr1);
  threefry2x32(0u, 1u, 0u, 2u, kn0, kn1);

  dim3 blk(256);
  const int gbU = (n_user + 127) / 128;
  const int gbS = (n_spot + 127) / 128;
  const int gb_e = (etot + 255) / 256;
  const int nb_scan = (NT + SCAN_E - 1) / SCAN_E;

  // CSR build (unified)
  hipMemsetAsync(deg_all, 0, (size_t)NT * 4, stream);
  hist3<<<gb_e, blk, 0, stream>>>(visit_dst, rev_dst, near_dst, deg_all,
                                  e_visit, e_rev, e_near, segU, segN);
  scanA<<<nb_scan, blk, 0, stream>>>(deg_all, bsum, NT);
  scanB<<<1, 1024, 0, stream>>>(bsum, rp_all, nb_scan, NT);
  scanC<<<nb_scan, blk, 0, stream>>>(deg_all, bsum, rp_all, cur_all, NT);
  fill3<<<gb_e, blk, 0, stream>>>(visit_src, visit_dst, rev_src, rev_dst,
                                  near_src, near_dst, cur_all, es_all,
                                  e_visit, e_rev, e_near, segU, segN);

  // fused source-side projections (one dispatch)
  proj3_gemm<<<gbU + 2 * gbS, blk, 0, stream>>>(
      x_user, x_spot, W_visit_src, W_rev_src, W_near_src,
      n_user, n_spot, proj_vs, proj_rs, proj_ns, gbU, gbS);

  // fused gather-reduce over all NT rows
  gather_reduce_all<<<(NT + 3) / 4, blk, 0, stream>>>(
      proj_vs, proj_rs, proj_ns, es_all, rp_all, accum_all,
      NT, segU, segN, emax, kv0, kv1, kr0, kr1, kn0, kn1);

  // fused finalize (one dispatch)
  final2_gemm<<<gbU + gbS, blk, 0, stream>>>(
      x_user, x_spot, W_rev_tgt, W_visit_tgt, W_near_tgt,
      n_user, n_spot, out_user, out_spot, mean_u, mean_sv, mean_sn, gbU);
}

// Round 9
// 557.263 us; speedup vs baseline: 7.5452x; 1.0047x over previous
//
#include <hip/hip_runtime.h>
#include <stdint.h>

#define DF 128
typedef unsigned short ushort_t;
typedef __attribute__((ext_vector_type(8))) short short8v;   // 8 bf16 (4 VGPRs)
typedef __attribute__((ext_vector_type(4))) float f32x4;

// ---------------- Threefry-2x32 (JAX-compatible, 20 rounds) ----------------
__host__ __device__ __forceinline__ unsigned rotl32(unsigned v, int r) {
  return __builtin_rotateleft32(v, (unsigned)r);   // fshl -> v_alignbit_b32
}

__host__ __device__ __forceinline__ void threefry2x32(
    unsigned k0, unsigned k1, unsigned c0, unsigned c1,
    unsigned& o0, unsigned& o1) {
  unsigned kx = k0 ^ k1 ^ 0x1BD11BDAu;
  unsigned x0 = c0 + k0;
  unsigned x1 = c1 + k1;
#define TF_R(r) { x0 += x1; x1 = rotl32(x1, r); x1 ^= x0; }
  TF_R(13) TF_R(15) TF_R(26) TF_R(6)
  x0 += k1; x1 += kx + 1u;
  TF_R(17) TF_R(29) TF_R(16) TF_R(24)
  x0 += kx; x1 += k0 + 2u;
  TF_R(13) TF_R(15) TF_R(26) TF_R(6)
  x0 += k0; x1 += k1 + 3u;
  TF_R(17) TF_R(29) TF_R(16) TF_R(24)
  x0 += k1; x1 += kx + 4u;
  TF_R(13) TF_R(15) TF_R(26) TF_R(6)
  x0 += kx; x1 += k0 + 5u;
#undef TF_R
  o0 = x0; o1 = x1;
}

#define KEEP_THR 0xE6666600u   // uniform(bits) < 0.9f

// ---------------- bf16 helpers (RTNE) --------------------------------------
__device__ __forceinline__ ushort_t f2bf(float f) {
  unsigned u = __float_as_uint(f);
  unsigned r = (u + 0x7fffu + ((u >> 16) & 1u)) >> 16;
  return (ushort_t)r;
}
__device__ __forceinline__ float bf2f(unsigned h) {
  return __uint_as_float(h << 16);
}

// =================== GEMM core ==============================================
// MFMA 16x16x32 bf16; C/D: col=lane&15, row=(lane>>4)*4+j.
#define WT(k, c) sm_u[(k) * 136 + (c)]
#define CTB(r, c) sm_u[(r) * 144 + (c)]       // bf16 repack (EPI0)
#define CTF(r, c) sm_f[(r) * 68 + (c)]        // f32 repack (col-half)

__device__ __forceinline__ void gemm_core(
    const float* __restrict__ X, const float* __restrict__ W1,
    const float* __restrict__ W2, bool sumW, int M, int rbase,
    ushort_t* sm_u, f32x4 acc[2][8]) {
  const int t = threadIdx.x;
  const int lane = t & 63;
  const int w = t >> 6;
  const int lr = lane & 15;
  const int kg = lane >> 4;

#pragma unroll
  for (int i = 0; i < 16; ++i) {
    int q = t + i * 256;
    int k = q >> 5;
    int c4 = (q & 31) * 4;
    float4 wv = *reinterpret_cast<const float4*>(&W1[k * DF + c4]);
    if (sumW) {
      float4 w2 = *reinterpret_cast<const float4*>(&W2[k * DF + c4]);
      wv.x += w2.x; wv.y += w2.y; wv.z += w2.z; wv.w += w2.w;
    }
    WT(c4 + 0, k) = f2bf(wv.x);
    WT(c4 + 1, k) = f2bf(wv.y);
    WT(c4 + 2, k) = f2bf(wv.z);
    WT(c4 + 3, k) = f2bf(wv.w);
  }
  __syncthreads();

#pragma unroll
  for (int rg = 0; rg < 2; ++rg)
#pragma unroll
    for (int n = 0; n < 8; ++n) acc[rg][n] = (f32x4){0.f, 0.f, 0.f, 0.f};

#pragma unroll
  for (int kt = 0; kt < 4; ++kt) {
    const int kb = kt * 32 + kg * 8;
    short8v a[2];
#pragma unroll
    for (int rg = 0; rg < 2; ++rg) {
      int r = rbase + w * 32 + rg * 16 + lr;
      float4 x0 = make_float4(0.f, 0.f, 0.f, 0.f);
      float4 x1 = x0;
      if (r < M) {
        x0 = *reinterpret_cast<const float4*>(&X[(size_t)r * DF + kb]);
        x1 = *reinterpret_cast<const float4*>(&X[(size_t)r * DF + kb + 4]);
      }
      short8v av;
      av[0] = (short)f2bf(x0.x); av[1] = (short)f2bf(x0.y);
      av[2] = (short)f2bf(x0.z); av[3] = (short)f2bf(x0.w);
      av[4] = (short)f2bf(x1.x); av[5] = (short)f2bf(x1.y);
      av[6] = (short)f2bf(x1.z); av[7] = (short)f2bf(x1.w);
      a[rg] = av;
    }
#pragma unroll
    for (int n = 0; n < 8; ++n) {
      short8v b = *reinterpret_cast<const short8v*>(&WT(n * 16 + lr, kb));
#pragma unroll
      for (int rg = 0; rg < 2; ++rg)
        acc[rg][n] = __builtin_amdgcn_mfma_f32_16x16x32_bf16(a[rg], b, acc[rg][n], 0, 0, 0);
    }
  }
}

// ---------------- fused: 3 source-projection GEMMs + edge histogram --------
__global__ __launch_bounds__(256) void proj3_hist(
    const float* __restrict__ x_user, const float* __restrict__ x_spot,
    const float* __restrict__ Wv, const float* __restrict__ Wr,
    const float* __restrict__ Wn, int n_user, int n_spot,
    ushort_t* __restrict__ pv, ushort_t* __restrict__ pr,
    ushort_t* __restrict__ pn, int gbU, int gbS,
    const int* __restrict__ vd, const int* __restrict__ rd,
    const int* __restrict__ nd, unsigned* __restrict__ deg_all,
    int Ev, int Er, int En, int segU, int segN, int gemmBlocks) {
  __shared__ __align__(16) ushort_t sm_u[18432];   // 36864 B
  const int b = blockIdx.x;

  if (b >= gemmBlocks) {
    // histogram role (memory/atomic-bound; overlaps GEMM blocks on other CUs)
    int i = (b - gemmBlocks) * 256 + threadIdx.x;
    if (i < Ev) atomicAdd(&deg_all[vd[i]], 1u);
    else if (i < Ev + Er) atomicAdd(&deg_all[segU + rd[i - Ev]], 1u);
    else if (i < Ev + Er + En) atomicAdd(&deg_all[segN + nd[i - Ev - Er]], 1u);
    return;
  }

  const float* X; const float* W; ushort_t* out; int M; int rbase;
  if (b < gbU)            { X = x_user; W = Wv; out = pv; M = n_user; rbase = b * 128; }
  else if (b < gbU + gbS) { X = x_spot; W = Wr; out = pr; M = n_spot; rbase = (b - gbU) * 128; }
  else                    { X = x_spot; W = Wn; out = pn; M = n_spot; rbase = (b - gbU - gbS) * 128; }

  f32x4 acc[2][8];
  gemm_core(X, W, nullptr, false, M, rbase, sm_u, acc);

  const int t = threadIdx.x;
  const int lane = t & 63;
  const int w = t >> 6;
  const int lr = lane & 15;
  const int kg = lane >> 4;

  __syncthreads();
#pragma unroll
  for (int rg = 0; rg < 2; ++rg) {
    const int rowb = w * 32 + rg * 16 + kg * 4;
#pragma unroll
    for (int n = 0; n < 8; ++n) {
      const int col = n * 16 + lr;
#pragma unroll
      for (int j = 0; j < 4; ++j) CTB(rowb + j, col) = f2bf(acc[rg][n][j]);
    }
  }
  __syncthreads();
#pragma unroll
  for (int i = 0; i < 8; ++i) {
    const int u = t + i * 256;
    const int row = u >> 4, ch = u & 15;
    const int grow = rbase + row;
    if (grow < M)
      *reinterpret_cast<uint4*>(&out[(size_t)grow * DF + ch * 8]) =
          *reinterpret_cast<const uint4*>(&CTB(row, ch * 8));
  }
}

// ---------------- fused finalize GEMM (EPI1 user / EPI2 spot) ---------------
__global__ __launch_bounds__(256) void final2_gemm(
    const float* __restrict__ x_user, const float* __restrict__ x_spot,
    const float* __restrict__ Wrt, const float* __restrict__ Wvt,
    const float* __restrict__ Wnt, int n_user, int n_spot,
    float* __restrict__ out_user, float* __restrict__ out_spot,
    const ushort_t* __restrict__ mean_u, const ushort_t* __restrict__ mean_sv,
    const ushort_t* __restrict__ mean_sn, int gbU) {
  __shared__ __align__(16) ushort_t sm_u[17408];
  float* sm_f_raw = reinterpret_cast<float*>(sm_u);
#define sm_f sm_f_raw
  const int b = blockIdx.x;
  const bool epi2 = (b >= gbU);
  const float* X; const float* W1; const float* W2; float* outF;
  const ushort_t* m1; const ushort_t* m2; int M; int rbase;
  if (!epi2) {
    X = x_user; W1 = Wrt; W2 = nullptr; outF = out_user;
    m1 = mean_u; m2 = nullptr; M = n_user; rbase = b * 128;
  } else {
    X = x_spot; W1 = Wvt; W2 = Wnt; outF = out_spot;
    m1 = mean_sv; m2 = mean_sn; M = n_spot; rbase = (b - gbU) * 128;
  }

  f32x4 acc[2][8];
  gemm_core(X, W1, W2, epi2, M, rbase, sm_u, acc);

  const int t = threadIdx.x;
  const int lane = t & 63;
  const int w = t >> 6;
  const int lr = lane & 15;
  const int kg = lane >> 4;

#pragma unroll
  for (int h = 0; h < 2; ++h) {
    __syncthreads();
#pragma unroll
    for (int rg = 0; rg < 2; ++rg) {
      const int rowb = w * 32 + rg * 16 + kg * 4;
#pragma unroll
      for (int n2 = 0; n2 < 4; ++n2) {
        const int n = h * 4 + n2;
        const int col = n2 * 16 + lr;
#pragma unroll
        for (int j = 0; j < 4; ++j) CTF(rowb + j, col) = acc[rg][n][j];
      }
    }
    __syncthreads();
#pragma unroll
    for (int i = 0; i < 8; ++i) {
      const int u = t + i * 256;
      const int row = u >> 4;
      const int c4 = (u & 15) * 4;
      const int grow = rbase + row;
      if (grow < M) {
        const float4 vv = *reinterpret_cast<const float4*>(&CTF(row, c4));
        const int col = h * 64 + c4;
        const uint2 mb = *reinterpret_cast<const uint2*>(&m1[(size_t)grow * DF + col]);
        float a0 = bf2f(mb.x & 0xffffu), a1 = bf2f(mb.x >> 16);
        float a2 = bf2f(mb.y & 0xffffu), a3 = bf2f(mb.y >> 16);
        float4 r;
        if (!epi2) {
          r.x = fmaxf(vv.x + a0, 0.f);
          r.y = fmaxf(vv.y + a1, 0.f);
          r.z = fmaxf(vv.z + a2, 0.f);
          r.w = fmaxf(vv.w + a3, 0.f);
        } else {
          const uint2 nb = *reinterpret_cast<const uint2*>(&m2[(size_t)grow * DF + col]);
          r.x = fmaxf(0.5f * (vv.x + a0 + bf2f(nb.x & 0xffffu)), 0.f);
          r.y = fmaxf(0.5f * (vv.y + a1 + bf2f(nb.x >> 16)), 0.f);
          r.z = fmaxf(0.5f * (vv.z + a2 + bf2f(nb.y & 0xffffu)), 0.f);
          r.w = fmaxf(0.5f * (vv.w + a3 + bf2f(nb.y >> 16)), 0.f);
        }
        *reinterpret_cast<float4*>(&outF[(size_t)grow * DF + col]) = r;
      }
    }
  }
#undef sm_f
}

// ---- scan: fused reduce + (last block) scan of partials --------------------
#define SCAN_E 2048   // 256 threads x 8 elems

__global__ __launch_bounds__(256) void scanAB(
    const unsigned* __restrict__ deg, unsigned* __restrict__ bsum,
    unsigned* __restrict__ rp_all, unsigned* __restrict__ done,
    int NT, int nb) {
  __shared__ unsigned sm[256];
  __shared__ int amLast;
  const int t = threadIdx.x;
  const int base = blockIdx.x * SCAN_E + t * 8;
  unsigned s = 0;
#pragma unroll
  for (int j = 0; j < 8; ++j) {
    int i = base + j;
    s += (i < NT) ? deg[i] : 0u;
  }
  sm[t] = s;
  __syncthreads();
  for (int off = 128; off; off >>= 1) {
    if (t < off) sm[t] += sm[t + off];
    __syncthreads();
  }
  if (t == 0) {
    bsum[blockIdx.x] = sm[0];
    __threadfence();
    unsigned prev = atomicAdd(done, 1u);
    amLast = (prev == (unsigned)(nb - 1));
  }
  __syncthreads();
  if (amLast) {
    __threadfence();   // acquire: see all blocks' bsum writes
    unsigned v = (t < nb) ? bsum[t] : 0u;
    __syncthreads();
    sm[t] = v;
    __syncthreads();
    for (int off = 1; off < 256; off <<= 1) {
      unsigned u = (t >= off) ? sm[t - off] : 0u;
      __syncthreads();
      sm[t] += u;
      __syncthreads();
    }
    if (t < nb) bsum[t] = sm[t] - v;          // exclusive
    if (t == nb - 1) rp_all[NT] = sm[t];      // grand total
  }
}

__global__ __launch_bounds__(256) void scanC(
    const unsigned* __restrict__ deg, const unsigned* __restrict__ bsum,
    unsigned* __restrict__ rp, unsigned* __restrict__ cur, int NT) {
  __shared__ unsigned sm[256];
  const int t = threadIdx.x;
  const int base = blockIdx.x * SCAN_E + t * 8;
  unsigned vals[8];
  unsigned s = 0;
#pragma unroll
  for (int j = 0; j < 8; ++j) {
    int i = base + j;
    vals[j] = (i < NT) ? deg[i] : 0u;
    s += vals[j];
  }
  sm[t] = s;
  __syncthreads();
  for (int off = 1; off < 256; off <<= 1) {
    unsigned u = (t >= off) ? sm[t - off] : 0u;
    __syncthreads();
    sm[t] += u;
    __syncthreads();
  }
  unsigned run = bsum[blockIdx.x] + sm[t] - s;
#pragma unroll
  for (int j = 0; j < 8; ++j) {
    int i = base + j;
    if (i < NT) { rp[i] = run; cur[i] = run; }
    run += vals[j];
  }
}

__global__ __launch_bounds__(256) void fill3(
    const int* __restrict__ vs, const int* __restrict__ vd,
    const int* __restrict__ rs, const int* __restrict__ rd,
    const int* __restrict__ ns, const int* __restrict__ nd,
    unsigned* __restrict__ cur_all, uint2* __restrict__ es_all,
    int Ev, int Er, int En, int segU, int segN) {
  int i = blockIdx.x * 256 + threadIdx.x;
  if (i < Ev) {
    unsigned slot = atomicAdd(&cur_all[vd[i]], 1u);
    es_all[slot] = make_uint2((unsigned)i, (unsigned)vs[i]);
  } else if (i < Ev + Er) {
    int e = i - Ev;
    unsigned slot = atomicAdd(&cur_all[segU + rd[e]], 1u);
    es_all[slot] = make_uint2((unsigned)e, (unsigned)rs[e]);
  } else if (i < Ev + Er + En) {
    int e = i - Ev - Er;
    unsigned slot = atomicAdd(&cur_all[segN + nd[e]], 1u);
    es_all[slot] = make_uint2((unsigned)e, (unsigned)ns[e]);
  }
}

// ---------------- fused gather-reduce: one wave per dst row -----------------
// Half-wave h processes edge 2p+h; per-lane vector es load (HW broadcast),
// 32-bit saddr+voffset addressing, validity scale folds the odd tail.
__global__ __launch_bounds__(256) void gather_reduce_all(
    const ushort_t* __restrict__ proj_v, const ushort_t* __restrict__ proj_r,
    const ushort_t* __restrict__ proj_n, const uint2* __restrict__ es,
    const unsigned* __restrict__ rp, ushort_t* __restrict__ accum_all,
    int NT, int segU, int segN, unsigned emax,
    unsigned kv0, unsigned kv1, unsigned kr0, unsigned kr1,
    unsigned kn0, unsigned kn1) {
  const int lane = threadIdx.x & 63;
  int d = blockIdx.x * 4 + (threadIdx.x >> 6);
  d = __builtin_amdgcn_readfirstlane(d);
  if (d >= NT) return;

  const ushort_t* proj;
  unsigned k0, k1;
  if (d < segU)      { proj = proj_v; k0 = kv0; k1 = kv1; }
  else if (d < segN) { proj = proj_r; k0 = kr0; k1 = kr1; }
  else               { proj = proj_n; k0 = kn0; k1 = kn1; }

  const unsigned b0 = __builtin_amdgcn_readfirstlane(rp[d]);
  const unsigned n  = __builtin_amdgcn_readfirstlane(rp[d + 1]) - b0;

  const unsigned hiadd = (unsigned)lane >> 5;        // 0 lo-half, 1 hi-half
  const unsigned l31 = (unsigned)(lane & 31);
  const unsigned voff8 = l31 * 8u;
  const unsigned niter = (n + 1u) >> 1;

  const char* es_c = reinterpret_cast<const char*>(es);
  const char* proj_c = reinterpret_cast<const char*>(proj);

  // prefetch pair 0 (per-lane; 32 lanes share one 8B entry -> broadcast)
  unsigned idx = min(b0 + hiadd, emax);
  uint2 E = *reinterpret_cast<const uint2*>(es_c + (size_t)(idx * 8u));

  float a0 = 0.f, a1 = 0.f, a2 = 0.f, a3 = 0.f;

  for (unsigned p = 0; p < niter; ++p) {
    const unsigned eid = E.x;
    const unsigned src = E.y;
    // prefetch next pair entry
    unsigned nidx = min(b0 + 2u * p + 2u + hiadd, emax);
    uint2 En = *reinterpret_cast<const uint2*>(es_c + (size_t)(nidx * 8u));
    // gather 4 features (8B) of this half's edge
    const uint2 g = *reinterpret_cast<const uint2*>(
        proj_c + (size_t)((src << 8) + voff8));
    // validity: edge index 2p+hiadd < n (folds the odd tail)
    const float sc = (2u * p + hiadd < n) ? (1.0f / 0.9f) : 0.f;

    const unsigned cb = (eid << 7) + l31 * 4u;
    unsigned r0a, r0b, r1a, r1b, r2a, r2b, r3a, r3b;
    threefry2x32(k0, k1, 0u, cb + 0u, r0a, r0b);
    threefry2x32(k0, k1, 0u, cb + 1u, r1a, r1b);
    threefry2x32(k0, k1, 0u, cb + 2u, r2a, r2b);
    threefry2x32(k0, k1, 0u, cb + 3u, r3a, r3b);
    const float m0 = ((r0a ^ r0b) < KEEP_THR) ? sc : 0.f;
    const float m1 = ((r1a ^ r1b) < KEEP_THR) ? sc : 0.f;
    const float m2 = ((r2a ^ r2b) < KEEP_THR) ? sc : 0.f;
    const float m3 = ((r3a ^ r3b) < KEEP_THR) ? sc : 0.f;
    a0 = fmaf(__uint_as_float(g.x << 16), m0, a0);
    a1 = fmaf(__uint_as_float(g.x & 0xffff0000u), m1, a1);
    a2 = fmaf(__uint_as_float(g.y << 16), m2, a2);
    a3 = fmaf(__uint_as_float(g.y & 0xffff0000u), m3, a3);

    E = En;
  }

  // combine the two half-wave partials (same features, different edges)
  a0 += __shfl_xor(a0, 32);
  a1 += __shfl_xor(a1, 32);
  a2 += __shfl_xor(a2, 32);
  a3 += __shfl_xor(a3, 32);

  const float inv = 1.0f / fmaxf((float)n, 1.0f);
  const float u0 = hiadd ? a2 : a0;
  const float u1 = hiadd ? a3 : a1;
  const unsigned pk =
      ((unsigned)f2bf(u0 * inv)) | (((unsigned)f2bf(u1 * inv)) << 16);
  unsigned* out = reinterpret_cast<unsigned*>(accum_all) + (size_t)d * 64;
  out[2u * l31 + hiadd] = pk;
}

// ---------------------------------------------------------------------------
extern "C" void kernel_launch(void* const* d_in, const int* in_sizes, int n_in,
                              void* d_out, int out_size, void* d_ws, size_t ws_size,
                              hipStream_t stream) {
  const float* x_user      = (const float*)d_in[0];
  const float* x_spot      = (const float*)d_in[1];
  const float* W_visit_src = (const float*)d_in[2];
  const float* W_visit_tgt = (const float*)d_in[3];
  const float* W_rev_src   = (const float*)d_in[4];
  const float* W_rev_tgt   = (const float*)d_in[5];
  const float* W_near_src  = (const float*)d_in[6];
  const float* W_near_tgt  = (const float*)d_in[7];
  const int* visit_src = (const int*)d_in[8];
  const int* visit_dst = (const int*)d_in[9];
  const int* rev_src   = (const int*)d_in[10];
  const int* rev_dst   = (const int*)d_in[11];
  const int* near_src  = (const int*)d_in[12];
  const int* near_dst  = (const int*)d_in[13];

  const int n_user = in_sizes[0] / DF;
  const int n_spot = in_sizes[1] / DF;
  const int e_visit = in_sizes[8];
  const int e_rev   = in_sizes[10];
  const int e_near  = in_sizes[12];

  float* out_user = (float*)d_out;
  float* out_spot = out_user + (size_t)n_user * DF;

  const int NT = n_spot + n_user + n_spot;
  const int segU = n_spot;
  const int segN = n_spot + n_user;
  const int etot = e_visit + e_rev + e_near;
  const unsigned emax = (unsigned)(etot - 1);

  // ---- workspace ----
  char* ws = (char*)d_ws;
  size_t off = 0;
  auto alloc = [&](size_t bytes) -> void* {
    void* p = ws + off;
    off += (bytes + 255) & ~(size_t)255;
    return p;
  };
  ushort_t* proj_vs   = (ushort_t*)alloc((size_t)n_user * DF * 2);
  ushort_t* proj_rs   = (ushort_t*)alloc((size_t)n_spot * DF * 2);
  ushort_t* proj_ns   = (ushort_t*)alloc((size_t)n_spot * DF * 2);
  ushort_t* accum_all = (ushort_t*)alloc((size_t)NT * DF * 2);
  uint2*    es_all    = (uint2*)   alloc((size_t)etot * 8);
  unsigned* rp_all    = (unsigned*)alloc(((size_t)NT + 1) * 4);
  unsigned* cur_all   = (unsigned*)alloc((size_t)NT * 4);
  unsigned* deg_all   = (unsigned*)alloc((size_t)NT * 4);
  unsigned* done      = (unsigned*)alloc(256);
  unsigned* bsum      = (unsigned*)alloc(4096);
  char* zero_end = (char*)bsum;   // memset deg_all..done (contiguous)

  ushort_t* mean_sv = accum_all;
  ushort_t* mean_u  = accum_all + (size_t)segU * DF;
  ushort_t* mean_sn = accum_all + (size_t)segN * DF;

  unsigned kv0, kv1, kr0, kr1, kn0, kn1;
  threefry2x32(0u, 1u, 0u, 0u, kv0, kv1);
  threefry2x32(0u, 1u, 0u, 1u, kr0, kr1);
  threefry2x32(0u, 1u, 0u, 2u, kn0, kn1);

  dim3 blk(256);
  const int gbU = (n_user + 127) / 128;
  const int gbS = (n_spot + 127) / 128;
  const int gb_e = (etot + 255) / 256;
  const int nb_scan = (NT + SCAN_E - 1) / SCAN_E;
  const int gemmBlocks = gbU + 2 * gbS;

  // zero deg_all + done counter (contiguous region)
  hipMemsetAsync(deg_all, 0, (size_t)(zero_end - (char*)deg_all), stream);

  // fused: 3 projection GEMMs + edge histogram (overlapping block roles)
  proj3_hist<<<gemmBlocks + gb_e, blk, 0, stream>>>(
      x_user, x_spot, W_visit_src, W_rev_src, W_near_src,
      n_user, n_spot, proj_vs, proj_rs, proj_ns, gbU, gbS,
      visit_dst, rev_dst, near_dst, deg_all,
      e_visit, e_rev, e_near, segU, segN, gemmBlocks);

  // scan (2 kernels: fused reduce+top-scan, then per-block rowptr/cursor)
  scanAB<<<nb_scan, blk, 0, stream>>>(deg_all, bsum, rp_all, done, NT, nb_scan);
  scanC<<<nb_scan, blk, 0, stream>>>(deg_all, bsum, rp_all, cur_all, NT);
  fill3<<<gb_e, blk, 0, stream>>>(visit_src, visit_dst, rev_src, rev_dst,
                                  near_src, near_dst, cur_all, es_all,
                                  e_visit, e_rev, e_near, segU, segN);

  // fused gather-reduce over all NT rows
  gather_reduce_all<<<(NT + 3) / 4, blk, 0, stream>>>(
      proj_vs, proj_rs, proj_ns, es_all, rp_all, accum_all,
      NT, segU, segN, emax, kv0, kv1, kr0, kr1, kn0, kn1);

  // fused finalize
  final2_gemm<<<gbU + gbS, blk, 0, stream>>>(
      x_user, x_spot, W_rev_tgt, W_visit_tgt, W_near_tgt,
      n_user, n_spot, out_user, out_spot, mean_u, mean_sv, mean_sn, gbU);
}

// Round 10
// 532.448 us; speedup vs baseline: 7.8968x; 1.0466x over previous
//
#include <hip/hip_runtime.h>
#include <stdint.h>

#define DF 128
typedef unsigned short ushort_t;
typedef __attribute__((ext_vector_type(8))) short short8v;   // 8 bf16 (4 VGPRs)
typedef __attribute__((ext_vector_type(4))) float f32x4;

// ---------------- Threefry-2x32 (JAX-compatible, 20 rounds) ----------------
__host__ __device__ __forceinline__ unsigned rotl32(unsigned v, int r) {
  return __builtin_rotateleft32(v, (unsigned)r);   // fshl -> v_alignbit_b32
}

__host__ __device__ __forceinline__ void threefry2x32(
    unsigned k0, unsigned k1, unsigned c0, unsigned c1,
    unsigned& o0, unsigned& o1) {
  unsigned kx = k0 ^ k1 ^ 0x1BD11BDAu;
  unsigned x0 = c0 + k0;
  unsigned x1 = c1 + k1;
#define TF_R(r) { x0 += x1; x1 = rotl32(x1, r); x1 ^= x0; }
  TF_R(13) TF_R(15) TF_R(26) TF_R(6)
  x0 += k1; x1 += kx + 1u;
  TF_R(17) TF_R(29) TF_R(16) TF_R(24)
  x0 += kx; x1 += k0 + 2u;
  TF_R(13) TF_R(15) TF_R(26) TF_R(6)
  x0 += k0; x1 += k1 + 3u;
  TF_R(17) TF_R(29) TF_R(16) TF_R(24)
  x0 += k1; x1 += kx + 4u;
  TF_R(13) TF_R(15) TF_R(26) TF_R(6)
  x0 += kx; x1 += k0 + 5u;
#undef TF_R
  o0 = x0; o1 = x1;
}

#define KEEP_THR 0xE6666600u   // uniform(bits) < 0.9f

// ---------------- bf16 helpers (RTNE) --------------------------------------
__device__ __forceinline__ ushort_t f2bf(float f) {
  unsigned u = __float_as_uint(f);
  unsigned r = (u + 0x7fffu + ((u >> 16) & 1u)) >> 16;
  return (ushort_t)r;
}
__device__ __forceinline__ float bf2f(unsigned h) {
  return __uint_as_float(h << 16);
}
__device__ __forceinline__ unsigned umin_u(unsigned a, unsigned b) {
  return a < b ? a : b;
}

// =================== GEMM core ==============================================
// MFMA 16x16x32 bf16; C/D: col=lane&15, row=(lane>>4)*4+j.
#define WT(k, c) sm_u[(k) * 136 + (c)]
#define CTB(r, c) sm_u[(r) * 144 + (c)]       // bf16 repack (EPI0)
#define CTF(r, c) sm_f[(r) * 68 + (c)]        // f32 repack (col-half)

__device__ __forceinline__ void gemm_core(
    const float* __restrict__ X, const float* __restrict__ W1,
    const float* __restrict__ W2, bool sumW, int M, int rbase,
    ushort_t* sm_u, f32x4 acc[2][8]) {
  const int t = threadIdx.x;
  const int lane = t & 63;
  const int w = t >> 6;
  const int lr = lane & 15;
  const int kg = lane >> 4;

#pragma unroll
  for (int i = 0; i < 16; ++i) {
    int q = t + i * 256;
    int k = q >> 5;
    int c4 = (q & 31) * 4;
    float4 wv = *reinterpret_cast<const float4*>(&W1[k * DF + c4]);
    if (sumW) {
      float4 w2 = *reinterpret_cast<const float4*>(&W2[k * DF + c4]);
      wv.x += w2.x; wv.y += w2.y; wv.z += w2.z; wv.w += w2.w;
    }
    WT(c4 + 0, k) = f2bf(wv.x);
    WT(c4 + 1, k) = f2bf(wv.y);
    WT(c4 + 2, k) = f2bf(wv.z);
    WT(c4 + 3, k) = f2bf(wv.w);
  }
  __syncthreads();

#pragma unroll
  for (int rg = 0; rg < 2; ++rg)
#pragma unroll
    for (int n = 0; n < 8; ++n) acc[rg][n] = (f32x4){0.f, 0.f, 0.f, 0.f};

#pragma unroll
  for (int kt = 0; kt < 4; ++kt) {
    const int kb = kt * 32 + kg * 8;
    short8v a[2];
#pragma unroll
    for (int rg = 0; rg < 2; ++rg) {
      int r = rbase + w * 32 + rg * 16 + lr;
      float4 x0 = make_float4(0.f, 0.f, 0.f, 0.f);
      float4 x1 = x0;
      if (r < M) {
        x0 = *reinterpret_cast<const float4*>(&X[(size_t)r * DF + kb]);
        x1 = *reinterpret_cast<const float4*>(&X[(size_t)r * DF + kb + 4]);
      }
      short8v av;
      av[0] = (short)f2bf(x0.x); av[1] = (short)f2bf(x0.y);
      av[2] = (short)f2bf(x0.z); av[3] = (short)f2bf(x0.w);
      av[4] = (short)f2bf(x1.x); av[5] = (short)f2bf(x1.y);
      av[6] = (short)f2bf(x1.z); av[7] = (short)f2bf(x1.w);
      a[rg] = av;
    }
#pragma unroll
    for (int n = 0; n < 8; ++n) {
      short8v b = *reinterpret_cast<const short8v*>(&WT(n * 16 + lr, kb));
#pragma unroll
      for (int rg = 0; rg < 2; ++rg)
        acc[rg][n] = __builtin_amdgcn_mfma_f32_16x16x32_bf16(a[rg], b, acc[rg][n], 0, 0, 0);
    }
  }
}

// ---------------- fused: 3 source-projection GEMMs + edge histogram --------
__global__ __launch_bounds__(256) void proj3_hist(
    const float* __restrict__ x_user, const float* __restrict__ x_spot,
    const float* __restrict__ Wv, const float* __restrict__ Wr,
    const float* __restrict__ Wn, int n_user, int n_spot,
    ushort_t* __restrict__ pv, ushort_t* __restrict__ pr,
    ushort_t* __restrict__ pn, int gbU, int gbS,
    const int* __restrict__ vd, const int* __restrict__ rd,
    const int* __restrict__ nd, unsigned* __restrict__ deg_all,
    int Ev, int Er, int En, int segU, int segN, int gemmBlocks) {
  __shared__ __align__(16) ushort_t sm_u[18432];   // 36864 B
  const int b = blockIdx.x;

  if (b >= gemmBlocks) {
    int i = (b - gemmBlocks) * 256 + threadIdx.x;
    if (i < Ev) atomicAdd(&deg_all[vd[i]], 1u);
    else if (i < Ev + Er) atomicAdd(&deg_all[segU + rd[i - Ev]], 1u);
    else if (i < Ev + Er + En) atomicAdd(&deg_all[segN + nd[i - Ev - Er]], 1u);
    return;
  }

  const float* X; const float* W; ushort_t* out; int M; int rbase;
  if (b < gbU)            { X = x_user; W = Wv; out = pv; M = n_user; rbase = b * 128; }
  else if (b < gbU + gbS) { X = x_spot; W = Wr; out = pr; M = n_spot; rbase = (b - gbU) * 128; }
  else                    { X = x_spot; W = Wn; out = pn; M = n_spot; rbase = (b - gbU - gbS) * 128; }

  f32x4 acc[2][8];
  gemm_core(X, W, nullptr, false, M, rbase, sm_u, acc);

  const int t = threadIdx.x;
  const int lane = t & 63;
  const int w = t >> 6;
  const int lr = lane & 15;
  const int kg = lane >> 4;

  __syncthreads();
#pragma unroll
  for (int rg = 0; rg < 2; ++rg) {
    const int rowb = w * 32 + rg * 16 + kg * 4;
#pragma unroll
    for (int n = 0; n < 8; ++n) {
      const int col = n * 16 + lr;
#pragma unroll
      for (int j = 0; j < 4; ++j) CTB(rowb + j, col) = f2bf(acc[rg][n][j]);
    }
  }
  __syncthreads();
#pragma unroll
  for (int i = 0; i < 8; ++i) {
    const int u = t + i * 256;
    const int row = u >> 4, ch = u & 15;
    const int grow = rbase + row;
    if (grow < M)
      *reinterpret_cast<uint4*>(&out[(size_t)grow * DF + ch * 8]) =
          *reinterpret_cast<const uint4*>(&CTB(row, ch * 8));
  }
}

// ---------------- fused finalize GEMM (EPI1 user / EPI2 spot) ---------------
__global__ __launch_bounds__(256) void final2_gemm(
    const float* __restrict__ x_user, const float* __restrict__ x_spot,
    const float* __restrict__ Wrt, const float* __restrict__ Wvt,
    const float* __restrict__ Wnt, int n_user, int n_spot,
    float* __restrict__ out_user, float* __restrict__ out_spot,
    const ushort_t* __restrict__ mean_u, const ushort_t* __restrict__ mean_sv,
    const ushort_t* __restrict__ mean_sn, int gbU) {
  __shared__ __align__(16) ushort_t sm_u[17408];
  float* sm_f_raw = reinterpret_cast<float*>(sm_u);
#define sm_f sm_f_raw
  const int b = blockIdx.x;
  const bool epi2 = (b >= gbU);
  const float* X; const float* W1; const float* W2; float* outF;
  const ushort_t* m1; const ushort_t* m2; int M; int rbase;
  if (!epi2) {
    X = x_user; W1 = Wrt; W2 = nullptr; outF = out_user;
    m1 = mean_u; m2 = nullptr; M = n_user; rbase = b * 128;
  } else {
    X = x_spot; W1 = Wvt; W2 = Wnt; outF = out_spot;
    m1 = mean_sv; m2 = mean_sn; M = n_spot; rbase = (b - gbU) * 128;
  }

  f32x4 acc[2][8];
  gemm_core(X, W1, W2, epi2, M, rbase, sm_u, acc);

  const int t = threadIdx.x;
  const int lane = t & 63;
  const int w = t >> 6;
  const int lr = lane & 15;
  const int kg = lane >> 4;

#pragma unroll
  for (int h = 0; h < 2; ++h) {
    __syncthreads();
#pragma unroll
    for (int rg = 0; rg < 2; ++rg) {
      const int rowb = w * 32 + rg * 16 + kg * 4;
#pragma unroll
      for (int n2 = 0; n2 < 4; ++n2) {
        const int n = h * 4 + n2;
        const int col = n2 * 16 + lr;
#pragma unroll
        for (int j = 0; j < 4; ++j) CTF(rowb + j, col) = acc[rg][n][j];
      }
    }
    __syncthreads();
#pragma unroll
    for (int i = 0; i < 8; ++i) {
      const int u = t + i * 256;
      const int row = u >> 4;
      const int c4 = (u & 15) * 4;
      const int grow = rbase + row;
      if (grow < M) {
        const float4 vv = *reinterpret_cast<const float4*>(&CTF(row, c4));
        const int col = h * 64 + c4;
        const uint2 mb = *reinterpret_cast<const uint2*>(&m1[(size_t)grow * DF + col]);
        float a0 = bf2f(mb.x & 0xffffu), a1 = bf2f(mb.x >> 16);
        float a2 = bf2f(mb.y & 0xffffu), a3 = bf2f(mb.y >> 16);
        float4 r;
        if (!epi2) {
          r.x = fmaxf(vv.x + a0, 0.f);
          r.y = fmaxf(vv.y + a1, 0.f);
          r.z = fmaxf(vv.z + a2, 0.f);
          r.w = fmaxf(vv.w + a3, 0.f);
        } else {
          const uint2 nb = *reinterpret_cast<const uint2*>(&m2[(size_t)grow * DF + col]);
          r.x = fmaxf(0.5f * (vv.x + a0 + bf2f(nb.x & 0xffffu)), 0.f);
          r.y = fmaxf(0.5f * (vv.y + a1 + bf2f(nb.x >> 16)), 0.f);
          r.z = fmaxf(0.5f * (vv.z + a2 + bf2f(nb.y & 0xffffu)), 0.f);
          r.w = fmaxf(0.5f * (vv.w + a3 + bf2f(nb.y >> 16)), 0.f);
        }
        *reinterpret_cast<float4*>(&outF[(size_t)grow * DF + col]) = r;
      }
    }
  }
#undef sm_f
}

// ---- single-kernel 2-level exclusive scan (last-block pattern + spin) ------
#define SCAN_E 2048   // 256 threads x 8 elems

__global__ __launch_bounds__(256) void scanABC(
    const unsigned* __restrict__ deg, unsigned* __restrict__ bsum,
    unsigned* __restrict__ bsumX, unsigned* __restrict__ rp,
    unsigned* __restrict__ cur, unsigned* __restrict__ done,
    int NT, int nb) {
  __shared__ unsigned sm[256];
  __shared__ int amLast;
  const int t = threadIdx.x;
  const int base = blockIdx.x * SCAN_E + t * 8;
  unsigned vals[8];
  unsigned s = 0;
#pragma unroll
  for (int j = 0; j < 8; ++j) {
    int i = base + j;
    vals[j] = (i < NT) ? deg[i] : 0u;
    s += vals[j];
  }
  // intra-block inclusive scan of per-thread sums
  sm[t] = s;
  __syncthreads();
  for (int off = 1; off < 256; off <<= 1) {
    unsigned u = (t >= off) ? sm[t - off] : 0u;
    __syncthreads();
    sm[t] += u;
    __syncthreads();
  }
  const unsigned myExcl = sm[t] - s;       // save before LDS reuse
  const unsigned blockTotal = sm[255];

  if (t == 0) {
    bsum[blockIdx.x] = blockTotal;
    __threadfence();
    unsigned prev = atomicAdd(&done[0], 1u);
    amLast = (prev == (unsigned)(nb - 1));
  }
  __syncthreads();

  if (amLast) {
    __threadfence();                       // see all blocks' bsum
    unsigned v = (t < nb) ? bsum[t] : 0u;  // own L1 only has own entry (write-through)
    __syncthreads();
    sm[t] = v;
    __syncthreads();
    for (int off = 1; off < 256; off <<= 1) {
      unsigned u = (t >= off) ? sm[t - off] : 0u;
      __syncthreads();
      sm[t] += u;
      __syncthreads();
    }
    if (t < nb) bsumX[t] = sm[t] - v;      // exclusive
    if (t == nb - 1) rp[NT] = sm[t];       // grand total
    __threadfence();
    if (t == 0) __hip_atomic_store(&done[1], 1u, __ATOMIC_RELEASE,
                                   __HIP_MEMORY_SCOPE_AGENT);
  }

  // all blocks wait for bsumX (co-resident: nb=98 <= 256 CUs)
  if (t == 0) {
    while (__hip_atomic_load(&done[1], __ATOMIC_ACQUIRE,
                             __HIP_MEMORY_SCOPE_AGENT) == 0u) {
      __builtin_amdgcn_s_sleep(8);
    }
  }
  __syncthreads();

  const unsigned bx = __hip_atomic_load(&bsumX[blockIdx.x], __ATOMIC_RELAXED,
                                        __HIP_MEMORY_SCOPE_AGENT);
  unsigned run = bx + myExcl;
#pragma unroll
  for (int j = 0; j < 8; ++j) {
    int i = base + j;
    if (i < NT) { rp[i] = run; cur[i] = run; }
    run += vals[j];
  }
}

__global__ __launch_bounds__(256) void fill3(
    const int* __restrict__ vs, const int* __restrict__ vd,
    const int* __restrict__ rs, const int* __restrict__ rd,
    const int* __restrict__ ns, const int* __restrict__ nd,
    unsigned* __restrict__ cur_all, uint2* __restrict__ es_all,
    int Ev, int Er, int En, int segU, int segN) {
  int i = blockIdx.x * 256 + threadIdx.x;
  if (i < Ev) {
    unsigned slot = atomicAdd(&cur_all[vd[i]], 1u);
    es_all[slot] = make_uint2((unsigned)i, (unsigned)vs[i]);
  } else if (i < Ev + Er) {
    int e = i - Ev;
    unsigned slot = atomicAdd(&cur_all[segU + rd[e]], 1u);
    es_all[slot] = make_uint2((unsigned)e, (unsigned)rs[e]);
  } else if (i < Ev + Er + En) {
    int e = i - Ev - Er;
    unsigned slot = atomicAdd(&cur_all[segN + nd[e]], 1u);
    es_all[slot] = make_uint2((unsigned)e, (unsigned)ns[e]);
  }
}

// ---------------- fused gather-reduce: one wave per dst row -----------------
// Round-7 structure (empirical optimum): lanes 0-31 edge i, lanes 32-63 edge
// i+1; scalar (readfirstlane) es pipeline; dwordx2 gather; shfl_xor combine.
__global__ __launch_bounds__(256) void gather_reduce_all(
    const ushort_t* __restrict__ proj_v, const ushort_t* __restrict__ proj_r,
    const ushort_t* __restrict__ proj_n, const uint2* __restrict__ es,
    const unsigned* __restrict__ rp, ushort_t* __restrict__ accum_all,
    int NT, int segU, int segN, unsigned emax,
    unsigned kv0, unsigned kv1, unsigned kr0, unsigned kr1,
    unsigned kn0, unsigned kn1) {
  const int lane = threadIdx.x & 63;
  int d = blockIdx.x * 4 + (threadIdx.x >> 6);
  d = __builtin_amdgcn_readfirstlane(d);
  if (d >= NT) return;

  const ushort_t* proj;
  unsigned k0, k1;
  if (d < segU)      { proj = proj_v; k0 = kv0; k1 = kv1; }
  else if (d < segN) { proj = proj_r; k0 = kr0; k1 = kr1; }
  else               { proj = proj_n; k0 = kn0; k1 = kn1; }

  const unsigned b0 = __builtin_amdgcn_readfirstlane(rp[d]);
  const unsigned n  = __builtin_amdgcn_readfirstlane(rp[d + 1]) - b0;

  const bool hi = lane >= 32;
  const unsigned l31 = (unsigned)(lane & 31);
  const unsigned voff8 = l31 * 8u;

  const unsigned npairs = n >> 1;
  const unsigned odd = n & 1u;

  uint2 P0 = es[umin_u(b0, emax)];
  uint2 P1 = es[umin_u(b0 + 1u, emax)];
  unsigned eA = __builtin_amdgcn_readfirstlane(P0.x);
  unsigned sA = __builtin_amdgcn_readfirstlane(P0.y);
  unsigned eB = __builtin_amdgcn_readfirstlane(P1.x);
  unsigned sB = __builtin_amdgcn_readfirstlane(P1.y);

  float a0 = 0.f, a1 = 0.f, a2 = 0.f, a3 = 0.f;

  for (unsigned p = 0; p < npairs; ++p) {
    const unsigned src = hi ? sB : sA;
    const unsigned eid = hi ? eB : eA;
    const uint2 g = *reinterpret_cast<const uint2*>(
        reinterpret_cast<const char*>(proj) + ((size_t)src << 8) + voff8);
    uint2 Pn0 = es[umin_u(b0 + 2u * p + 2u, emax)];
    uint2 Pn1 = es[umin_u(b0 + 2u * p + 3u, emax)];

    const unsigned cb = eid * 128u + l31 * 4u;
    unsigned r0a, r0b, r1a, r1b, r2a, r2b, r3a, r3b;
    threefry2x32(k0, k1, 0u, cb + 0u, r0a, r0b);
    threefry2x32(k0, k1, 0u, cb + 1u, r1a, r1b);
    threefry2x32(k0, k1, 0u, cb + 2u, r2a, r2b);
    threefry2x32(k0, k1, 0u, cb + 3u, r3a, r3b);
    const float m0 = ((r0a ^ r0b) < KEEP_THR) ? (1.0f / 0.9f) : 0.f;
    const float m1 = ((r1a ^ r1b) < KEEP_THR) ? (1.0f / 0.9f) : 0.f;
    const float m2 = ((r2a ^ r2b) < KEEP_THR) ? (1.0f / 0.9f) : 0.f;
    const float m3 = ((r3a ^ r3b) < KEEP_THR) ? (1.0f / 0.9f) : 0.f;
    a0 = fmaf(__uint_as_float(g.x << 16), m0, a0);
    a1 = fmaf(__uint_as_float(g.x & 0xffff0000u), m1, a1);
    a2 = fmaf(__uint_as_float(g.y << 16), m2, a2);
    a3 = fmaf(__uint_as_float(g.y & 0xffff0000u), m3, a3);

    eA = __builtin_amdgcn_readfirstlane(Pn0.x);
    sA = __builtin_amdgcn_readfirstlane(Pn0.y);
    eB = __builtin_amdgcn_readfirstlane(Pn1.x);
    sB = __builtin_amdgcn_readfirstlane(Pn1.y);
  }

  if (odd) {
    const uint2 g = *reinterpret_cast<const uint2*>(
        reinterpret_cast<const char*>(proj) + ((size_t)sA << 8) + voff8);
    const unsigned cb = eA * 128u + l31 * 4u;
    unsigned r0a, r0b, r1a, r1b, r2a, r2b, r3a, r3b;
    threefry2x32(k0, k1, 0u, cb + 0u, r0a, r0b);
    threefry2x32(k0, k1, 0u, cb + 1u, r1a, r1b);
    threefry2x32(k0, k1, 0u, cb + 2u, r2a, r2b);
    threefry2x32(k0, k1, 0u, cb + 3u, r3a, r3b);
    const float sc = hi ? 0.f : (1.0f / 0.9f);
    const float m0 = ((r0a ^ r0b) < KEEP_THR) ? sc : 0.f;
    const float m1 = ((r1a ^ r1b) < KEEP_THR) ? sc : 0.f;
    const float m2 = ((r2a ^ r2b) < KEEP_THR) ? sc : 0.f;
    const float m3 = ((r3a ^ r3b) < KEEP_THR) ? sc : 0.f;
    a0 = fmaf(__uint_as_float(g.x << 16), m0, a0);
    a1 = fmaf(__uint_as_float(g.x & 0xffff0000u), m1, a1);
    a2 = fmaf(__uint_as_float(g.y << 16), m2, a2);
    a3 = fmaf(__uint_as_float(g.y & 0xffff0000u), m3, a3);
  }

  a0 += __shfl_xor(a0, 32);
  a1 += __shfl_xor(a1, 32);
  a2 += __shfl_xor(a2, 32);
  a3 += __shfl_xor(a3, 32);

  const float inv = 1.0f / fmaxf((float)n, 1.0f);
  const float u0 = hi ? a2 : a0;
  const float u1 = hi ? a3 : a1;
  const unsigned pk =
      ((unsigned)f2bf(u0 * inv)) | (((unsigned)f2bf(u1 * inv)) << 16);
  unsigned* out = reinterpret_cast<unsigned*>(accum_all) + (size_t)d * 64;
  out[2u * l31 + (hi ? 1u : 0u)] = pk;
}

// ---------------------------------------------------------------------------
extern "C" void kernel_launch(void* const* d_in, const int* in_sizes, int n_in,
                              void* d_out, int out_size, void* d_ws, size_t ws_size,
                              hipStream_t stream) {
  const float* x_user      = (const float*)d_in[0];
  const float* x_spot      = (const float*)d_in[1];
  const float* W_visit_src = (const float*)d_in[2];
  const float* W_visit_tgt = (const float*)d_in[3];
  const float* W_rev_src   = (const float*)d_in[4];
  const float* W_rev_tgt   = (const float*)d_in[5];
  const float* W_near_src  = (const float*)d_in[6];
  const float* W_near_tgt  = (const float*)d_in[7];
  const int* visit_src = (const int*)d_in[8];
  const int* visit_dst = (const int*)d_in[9];
  const int* rev_src   = (const int*)d_in[10];
  const int* rev_dst   = (const int*)d_in[11];
  const int* near_src  = (const int*)d_in[12];
  const int* near_dst  = (const int*)d_in[13];

  const int n_user = in_sizes[0] / DF;
  const int n_spot = in_sizes[1] / DF;
  const int e_visit = in_sizes[8];
  const int e_rev   = in_sizes[10];
  const int e_near  = in_sizes[12];

  float* out_user = (float*)d_out;
  float* out_spot = out_user + (size_t)n_user * DF;

  const int NT = n_spot + n_user + n_spot;
  const int segU = n_spot;
  const int segN = n_spot + n_user;
  const int etot = e_visit + e_rev + e_near;
  const unsigned emax = (unsigned)(etot - 1);

  // ---- workspace ----
  char* ws = (char*)d_ws;
  size_t off = 0;
  auto alloc = [&](size_t bytes) -> void* {
    void* p = ws + off;
    off += (bytes + 255) & ~(size_t)255;
    return p;
  };
  ushort_t* proj_vs   = (ushort_t*)alloc((size_t)n_user * DF * 2);
  ushort_t* proj_rs   = (ushort_t*)alloc((size_t)n_spot * DF * 2);
  ushort_t* proj_ns   = (ushort_t*)alloc((size_t)n_spot * DF * 2);
  ushort_t* accum_all = (ushort_t*)alloc((size_t)NT * DF * 2);
  uint2*    es_all    = (uint2*)   alloc((size_t)etot * 8);
  unsigned* rp_all    = (unsigned*)alloc(((size_t)NT + 1) * 4);
  unsigned* cur_all   = (unsigned*)alloc((size_t)NT * 4);
  unsigned* deg_all   = (unsigned*)alloc((size_t)NT * 4);
  unsigned* done      = (unsigned*)alloc(256);    // done[0]=counter, done[1]=flag
  unsigned* bsum      = (unsigned*)alloc(4096);   // not zeroed (fully written)
  unsigned* bsumX     = (unsigned*)alloc(4096);
  char* zero_end = (char*)bsum;   // memset deg_all..done (contiguous)

  ushort_t* mean_sv = accum_all;
  ushort_t* mean_u  = accum_all + (size_t)segU * DF;
  ushort_t* mean_sn = accum_all + (size_t)segN * DF;

  unsigned kv0, kv1, kr0, kr1, kn0, kn1;
  threefry2x32(0u, 1u, 0u, 0u, kv0, kv1);
  threefry2x32(0u, 1u, 0u, 1u, kr0, kr1);
  threefry2x32(0u, 1u, 0u, 2u, kn0, kn1);

  dim3 blk(256);
  const int gbU = (n_user + 127) / 128;
  const int gbS = (n_spot + 127) / 128;
  const int gb_e = (etot + 255) / 256;
  const int nb_scan = (NT + SCAN_E - 1) / SCAN_E;
  const int gemmBlocks = gbU + 2 * gbS;

  // zero deg_all + done counters (contiguous region)
  hipMemsetAsync(deg_all, 0, (size_t)(zero_end - (char*)deg_all), stream);

  // fused: 3 projection GEMMs + edge histogram (overlapping block roles)
  proj3_hist<<<gemmBlocks + gb_e, blk, 0, stream>>>(
      x_user, x_spot, W_visit_src, W_rev_src, W_near_src,
      n_user, n_spot, proj_vs, proj_rs, proj_ns, gbU, gbS,
      visit_dst, rev_dst, near_dst, deg_all,
      e_visit, e_rev, e_near, segU, segN, gemmBlocks);

  // single-kernel 2-level scan -> rowptr + cursors
  scanABC<<<nb_scan, blk, 0, stream>>>(deg_all, bsum, bsumX, rp_all, cur_all,
                                       done, NT, nb_scan);
  fill3<<<gb_e, blk, 0, stream>>>(visit_src, visit_dst, rev_src, rev_dst,
                                  near_src, near_dst, cur_all, es_all,
                                  e_visit, e_rev, e_near, segU, segN);

  // fused gather-reduce over all NT rows
  gather_reduce_all<<<(NT + 3) / 4, blk, 0, stream>>>(
      proj_vs, proj_rs, proj_ns, es_all, rp_all, accum_all,
      NT, segU, segN, emax, kv0, kv1, kr0, kr1, kn0, kn1);

  // fused finalize
  final2_gemm<<<gbU + gbS, blk, 0, stream>>>(
      x_user, x_spot, W_rev_tgt, W_visit_tgt, W_near_tgt,
      n_user, n_spot, out_user, out_spot, mean_u, mean_sv, mean_sn, gbU);
}